// Round 3
// baseline (416.552 us; speedup 1.0000x reference)
//
#include <hip/hip_runtime.h>

#define S_LEN 2048
#define EMB 2048
#define NH 16
#define KVH 4
#define DH 128

typedef __bf16 bf16x8 __attribute__((ext_vector_type(8)));
typedef float floatx4 __attribute__((ext_vector_type(4)));
typedef unsigned short ushortx8 __attribute__((ext_vector_type(8)));
typedef unsigned short ushortx4 __attribute__((ext_vector_type(4)));

static __device__ __forceinline__ unsigned short f2bf(float f) {
  unsigned u = __float_as_uint(f);
  return (unsigned short)((u + 0x7fffu + ((u >> 16) & 1u)) >> 16);
}

// async 16B global -> LDS (wave-uniform LDS base + lane*16)
static __device__ __forceinline__ void gload16(const unsigned short* g, unsigned short* l) {
  __builtin_amdgcn_global_load_lds(
      (const __attribute__((address_space(1))) unsigned int*)(const void*)g,
      (__attribute__((address_space(3))) unsigned int*)(void*)l, 16, 0, 0);
}

// ---- fused preprocessing: qkv fp32->bf16 (blocks 0..12287) + weight
// ---- transpose/scale/convert to [N][K] bf16 (blocks 12288..22527)
__global__ __launch_bounds__(256) void pre_kernel(
    const float* __restrict__ q, const float* __restrict__ k, const float* __restrict__ v,
    const float* __restrict__ Wq, const float* __restrict__ Wk,
    const float* __restrict__ Wv, const float* __restrict__ Wo,
    unsigned short* __restrict__ qo, unsigned short* __restrict__ ko,
    unsigned short* __restrict__ vo,
    unsigned short* __restrict__ Wqt, unsigned short* __restrict__ Wkt,
    unsigned short* __restrict__ Wvt, unsigned short* __restrict__ Wot,
    float scale) {
  __shared__ float t[32][33];
  int bx = blockIdx.x;
  if (bx < 12288) {
    const int sel = bx >> 12;
    const float* in = (sel == 0) ? q : (sel == 1) ? k : v;
    unsigned short* out = (sel == 0) ? qo : (sel == 1) ? ko : vo;
    size_t i = (((size_t)(bx & 4095)) * 256 + threadIdx.x) * 8;
    floatx4 a = *(const floatx4*)(in + i);
    floatx4 bvec = *(const floatx4*)(in + i + 4);
    ushortx8 o;
    #pragma unroll
    for (int c = 0; c < 4; ++c) { o[c] = f2bf(a[c]); o[4 + c] = f2bf(bvec[c]); }
    *(ushortx8*)(out + i) = o;
  } else {
    bx -= 12288;
    const float* W; unsigned short* Wt; int N, tile; float sc;
    if (bx < 4096)      { W = Wq; Wt = Wqt; N = 2048; tile = bx;        sc = scale; }
    else if (bx < 5120) { W = Wk; Wt = Wkt; N = 512;  tile = bx - 4096; sc = scale; }
    else if (bx < 6144) { W = Wv; Wt = Wvt; N = 512;  tile = bx - 5120; sc = 1.0f; }
    else                { W = Wo; Wt = Wot; N = 2048; tile = bx - 6144; sc = 1.0f; }
    const int ntiles = N >> 5;
    const int n0 = (tile % ntiles) * 32, k0 = (tile / ntiles) * 32;
    const int tx = threadIdx.x & 31, ty = threadIdx.x >> 5;
    #pragma unroll
    for (int r = 0; r < 4; ++r)
      t[ty + r * 8][tx] = W[(size_t)(k0 + ty + r * 8) * N + n0 + tx];
    __syncthreads();
    #pragma unroll
    for (int r = 0; r < 4; ++r)
      Wt[(size_t)(n0 + ty + r * 8) * 2048 + k0 + tx] = f2bf(t[tx][ty + r * 8] * sc);
  }
}

// ================= 256x256 / BK=64 / 8-wave / 8-phase GEMM core =================
// Spread-staging schedule (body t reads buf p=t&1, other buf q):
//  P1: ds_read op1 c0 (8) + o2a (4) | stage A(t+1)h1 -> q | BAR lgkm0 MFMA[o2a01] BAR
//  P2: ds_read o2b (4)              | stage B(t+1)h0 -> q | BAR lgkm0 MFMA[o2a23] BAR
//  P3: ds_read op1 c1 (8)           | stage B(t+1)h1 -> q | BAR lgkm0 MFMA[o2b01] BAR
//  P4: stage A(t+2)h0 -> p | BAR | MFMA[o2b23] | vmcnt(2) | BAR
// Safety: writes to q in P1-P3 target data last read in body t-1 (drained at each
// wave's t-1.P3 lgkm0, all waves past t-1's final barrier). Write to p in P4 is
// after the P3-end barrier (all waves' reads of p drained). vmcnt(2) at P4 drains
// all of S(t+1) (8 loads) keeping A(t+2)h0 (2) in flight -> counted, never 0.
static __device__ __forceinline__ void gemm256_core(
    const unsigned short* __restrict__ Ab, const unsigned short* __restrict__ Bb,
    bool swap, unsigned short* As, unsigned short* Bs, floatx4 (&acc)[8][4]) {
  const int tid = threadIdx.x;
  const int lane = tid & 63, w = tid >> 6;
  const int lm = lane & 15, gq = lane >> 4;
  const int wm = w >> 2, wn = w & 3;
  const int lr = lane >> 3, lc = (lane & 7) ^ lr;

  auto stageH = [&](const unsigned short* gb, unsigned short* lt, int half, int kst) {
    #pragma unroll
    for (int qq = 0; qq < 2; ++qq) {
      const int rb = half * 128 + w * 16 + qq * 8;
      gload16(gb + (((size_t)(rb + lr)) << 11) + kst + (lc << 3), lt + rb * 64);
    }
  };

  unsigned short* As2 = As + 16384;
  unsigned short* Bs2 = Bs + 16384;

  // prologue: tile0 (all 4 halves) -> buf0; A(1)h0 -> buf1
  stageH(Ab, As, 0, 0);  stageH(Ab, As, 1, 0);
  stageH(Bb, Bs, 0, 0);  stageH(Bb, Bs, 1, 0);
  stageH(Ab, As2, 0, 64);
  asm volatile("s_waitcnt vmcnt(2)" ::: "memory");
  __builtin_amdgcn_s_barrier();

  const int r1 = (wm * 128 + lm) * 64;             // op1 row base (frag i: +i*1024)
  const int r2 = (wn * 64 + lm) * 64;              // op2 row base (frag j: +j*1024)
  const int c0 = ((0 + gq) ^ (lm & 7)) * 8;        // kk0 chunk (XOR-swizzled)
  const int c1 = ((4 + gq) ^ (lm & 7)) * 8;        // kk1 chunk

#define TILE_BODY(CA, CB, OA, OB, KS1, KS2, STG1, STG4)                                         \
  {                                                                                             \
    const unsigned short* l1 = swap ? (CB) : (CA);                                              \
    const unsigned short* l2 = swap ? (CA) : (CB);                                              \
    bf16x8 op1[8], o2a[4], o2b[4];                                                              \
    _Pragma("unroll") for (int i = 0; i < 8; ++i)                                               \
      op1[i] = *(const bf16x8*)&l1[r1 + i * 1024 + c0];                                         \
    _Pragma("unroll") for (int j = 0; j < 4; ++j)                                               \
      o2a[j] = *(const bf16x8*)&l2[r2 + j * 1024 + c0];                                         \
    if (STG1) stageH(Ab, (OA), 1, (KS1));                                                       \
    __builtin_amdgcn_s_barrier();                                                               \
    asm volatile("s_waitcnt lgkmcnt(0)" ::: "memory");                                          \
    __builtin_amdgcn_s_setprio(1);                                                              \
    _Pragma("unroll") for (int i = 0; i < 8; ++i) {                                             \
      acc[i][0] = __builtin_amdgcn_mfma_f32_16x16x32_bf16(op1[i], o2a[0], acc[i][0], 0, 0, 0);  \
      acc[i][1] = __builtin_amdgcn_mfma_f32_16x16x32_bf16(op1[i], o2a[1], acc[i][1], 0, 0, 0);  \
    }                                                                                           \
    __builtin_amdgcn_s_setprio(0);                                                              \
    __builtin_amdgcn_s_barrier();                                                               \
    _Pragma("unroll") for (int j = 0; j < 4; ++j)                                               \
      o2b[j] = *(const bf16x8*)&l2[r2 + j * 1024 + c1];                                         \
    if (STG1) stageH(Bb, (OB), 0, (KS1));                                                       \
    __builtin_amdgcn_s_barrier();                                                               \
    asm volatile("s_waitcnt lgkmcnt(0)" ::: "memory");                                          \
    __builtin_amdgcn_s_setprio(1);                                                              \
    _Pragma("unroll") for (int i = 0; i < 8; ++i) {                                             \
      acc[i][2] = __builtin_amdgcn_mfma_f32_16x16x32_bf16(op1[i], o2a[2], acc[i][2], 0, 0, 0);  \
      acc[i][3] = __builtin_amdgcn_mfma_f32_16x16x32_bf16(op1[i], o2a[3], acc[i][3], 0, 0, 0);  \
    }                                                                                           \
    __builtin_amdgcn_s_setprio(0);                                                              \
    __builtin_amdgcn_s_barrier();                                                               \
    _Pragma("unroll") for (int i = 0; i < 8; ++i)                                               \
      op1[i] = *(const bf16x8*)&l1[r1 + i * 1024 + c1];                                         \
    if (STG1) stageH(Bb, (OB), 1, (KS1));                                                       \
    __builtin_amdgcn_s_barrier();                                                               \
    asm volatile("s_waitcnt lgkmcnt(0)" ::: "memory");                                          \
    __builtin_amdgcn_s_setprio(1);                                                              \
    _Pragma("unroll") for (int i = 0; i < 8; ++i) {                                             \
      acc[i][0] = __builtin_amdgcn_mfma_f32_16x16x32_bf16(op1[i], o2b[0], acc[i][0], 0, 0, 0);  \
      acc[i][1] = __builtin_amdgcn_mfma_f32_16x16x32_bf16(op1[i], o2b[1], acc[i][1], 0, 0, 0);  \
    }                                                                                           \
    __builtin_amdgcn_s_setprio(0);                                                              \
    __builtin_amdgcn_s_barrier();                                                               \
    if (STG4) stageH(Ab, (CA), 0, (KS2));                                                       \
    __builtin_amdgcn_s_barrier();                                                               \
    __builtin_amdgcn_s_setprio(1);                                                              \
    _Pragma("unroll") for (int i = 0; i < 8; ++i) {                                             \
      acc[i][2] = __builtin_amdgcn_mfma_f32_16x16x32_bf16(op1[i], o2b[2], acc[i][2], 0, 0, 0);  \
      acc[i][3] = __builtin_amdgcn_mfma_f32_16x16x32_bf16(op1[i], o2b[3], acc[i][3], 0, 0, 0);  \
    }                                                                                           \
    __builtin_amdgcn_s_setprio(0);                                                              \
    if (STG4) { asm volatile("s_waitcnt vmcnt(2)" ::: "memory"); }                              \
    else      { asm volatile("s_waitcnt vmcnt(0)" ::: "memory"); }                              \
    __builtin_amdgcn_s_barrier();                                                               \
  }

  #pragma unroll 1
  for (int t = 0; t < 30; t += 2) {
    TILE_BODY(As, Bs, As2, Bs2, (t + 1) * 64, (t + 2) * 64, 1, 1);
    TILE_BODY(As2, Bs2, As, Bs, (t + 2) * 64, (t + 3) * 64, 1, 1);
  }
  TILE_BODY(As, Bs, As2, Bs2, 31 * 64, 0, 1, 0);
  TILE_BODY(As2, Bs2, As, Bs, 0, 0, 0, 0);
#undef TILE_BODY
}

// ---- merged Q/K/V projection GEMM: 192 blocks of 256x256, K=2048 ----
// Q,K swapped (op1=W -> reg dim = d); V normal (op1=data -> reg dim = s).
__global__ __launch_bounds__(512, 2) void proj_kernel(
    const unsigned short* __restrict__ qb, const unsigned short* __restrict__ kb,
    const unsigned short* __restrict__ vb,
    const unsigned short* __restrict__ Wqt, const unsigned short* __restrict__ Wkt,
    const unsigned short* __restrict__ Wvt,
    unsigned short* __restrict__ Qh, unsigned short* __restrict__ Kh,
    unsigned short* __restrict__ Vt) {
  extern __shared__ unsigned short lds[];
  unsigned short* As = lds;            // 2 x 16384
  unsigned short* Bs = lds + 32768;    // 2 x 16384
  int bid = (int)blockIdx.x;
  bid = (bid & 7) * 24 + (bid >> 3);   // XCD swizzle (192 % 8 == 0 -> bijective)
  const unsigned short *Ab, *Bb;
  int task, bn, bt;
  if (bid < 128)      { task = 0; bn = bid >> 4;         bt = bid & 15;         Ab = qb; Bb = Wqt; }
  else if (bid < 160) { task = 1; bn = (bid - 128) >> 4; bt = (bid - 128) & 15; Ab = kb; Bb = Wkt; }
  else                { task = 2; bn = (bid - 160) >> 4; bt = (bid - 160) & 15; Ab = vb; Bb = Wvt; }
  Ab += ((size_t)bt) << 19;   // bt*256*2048
  Bb += ((size_t)bn) << 19;

  floatx4 acc[8][4] = {};
  gemm256_core(Ab, Bb, task != 2, As, Bs, acc);

  const int tid = threadIdx.x, lane = tid & 63, w = tid >> 6;
  const int lm = lane & 15, gq = lane >> 4;
  const int wm = w >> 2, wn = w & 3;
  if (task != 2) {           // Q/K: rows=d (weight n-dim), cols=t
    unsigned short* outp = (task == 0) ? Qh : Kh;
    const int nheads = (task == 0) ? NH : KVH;
    const int head = bn * 2 + wm;
    #pragma unroll
    for (int i = 0; i < 8; ++i) {
      const int d0 = i * 16 + gq * 4;
      #pragma unroll
      for (int j = 0; j < 4; ++j) {
        const int tg = bt * 256 + wn * 64 + j * 16 + lm;
        const int b_ = tg >> 11, s_ = tg & 2047;
        ushortx4 pk;
        #pragma unroll
        for (int r = 0; r < 4; ++r) pk[r] = f2bf(acc[i][j][r]);
        *(ushortx4*)&outp[((size_t)(b_ * nheads + head) * S_LEN + s_) * DH + d0] = pk;
      }
    }
  } else {                   // V: rows=s, cols=d -> Vt [B,KVH,D,S]
    #pragma unroll
    for (int i = 0; i < 8; ++i) {
      const int sgl = bt * 256 + wm * 128 + i * 16 + gq * 4;
      const int b_ = sgl >> 11, s_ = sgl & 2047;
      #pragma unroll
      for (int j = 0; j < 4; ++j) {
        const int dl = wn * 64 + j * 16;
        const int head = bn * 2 + (dl >> 7);
        const int dd = (dl & 127) + lm;
        ushortx4 pk;
        #pragma unroll
        for (int r = 0; r < 4; ++r) pk[r] = f2bf(acc[i][j][r]);
        *(ushortx4*)&Vt[((size_t)(b_ * KVH + head) * DH + dd) * S_LEN + s_] = pk;
      }
    }
  }
}

// ---- final GEMM: out[t][n] fp32 = Z[t][k] * Wot[n][k]^T, 128 blocks 256x256 ----
__global__ __launch_bounds__(512, 2) void out_kernel(const unsigned short* __restrict__ Z,
                                                     const unsigned short* __restrict__ Wot,
                                                     float* __restrict__ outp) {
  extern __shared__ unsigned short lds[];
  unsigned short* As = lds;
  unsigned short* Bs = lds + 32768;
  int bid = (int)blockIdx.x;
  bid = (bid & 7) * 16 + (bid >> 3);   // XCD swizzle (128 % 8 == 0)
  const int bn = bid >> 4, bt = bid & 15;

  floatx4 acc[8][4] = {};
  gemm256_core(Z + (((size_t)bt) << 19), Wot + (((size_t)bn) << 19), true, As, Bs, acc);

  const int tid = threadIdx.x, lane = tid & 63, w = tid >> 6;
  const int lm = lane & 15, gq = lane >> 4;
  const int wm = w >> 2, wn = w & 3;
  #pragma unroll
  for (int i = 0; i < 8; ++i) {
    const int n0 = bn * 256 + wm * 128 + i * 16 + gq * 4;
    #pragma unroll
    for (int j = 0; j < 4; ++j) {
      const int tg = bt * 256 + wn * 64 + j * 16 + lm;
      *(floatx4*)&outp[(size_t)tg * 2048 + n0] = acc[i][j];
    }
  }
}

// ---- flash-style causal attention, LDS-minimal:
// K: per-wave register fragments loaded straight from global (L2-served),
//    single-buffered; next-tile loads issue right after QK^T consumes regs.
// V: DMA-staged (global_load_lds) into linear [128][64] double buffer with
//    source-side XOR chunk swizzle (sigma = c ^ (d&7)); reads apply same XOR
//    -> conflict-free b128 reads, zero ds_write instructions.
// One barrier per iter with counted vmcnt(16) (drains 4 V-DMAs, keeps 16
// K-loads in flight).
__global__ __launch_bounds__(256) void attn_kernel(const unsigned short* __restrict__ Qh,
                                                   const unsigned short* __restrict__ Kh,
                                                   const unsigned short* __restrict__ Vt,
                                                   unsigned short* __restrict__ Z) {
  __shared__ unsigned short Vs[2][128 * 64];
  __shared__ unsigned short Ps[4][16][88];  // stride 88: ~2-way u16 writes, min b128 reads
  const int tid = threadIdx.x;
  const int w = tid >> 6, lane = tid & 63;
  const int lm = lane & 15, gq = lane >> 4;
  const int h = blockIdx.y, b = blockIdx.z;
  const unsigned short* Kp = Kh + (size_t)(b * KVH + (h >> 2)) * S_LEN * DH;
  const unsigned short* Vp = Vt + (size_t)(b * KVH + (h >> 2)) * DH * S_LEN;

  // V DMA mapping: instr i -> dest chunk idx = i*256+tid -> (d = i*32 + (tid>>3),
  // c = tid&7); source chunk sigma = c ^ (d&7)  (i*32 doesn't affect d&7)
  const int vrow8 = tid >> 3;
  const int vsig = (tid & 7) ^ (vrow8 & 7);
  const unsigned short* vsrc0 = Vp + (size_t)vrow8 * S_LEN + vsig * 8;

  bf16x8 kreg[16];
  const unsigned short* kf0 = Kp + (size_t)lm * DH + gq * 8;

  auto loadV = [&](int kvn, int bsel) {
    unsigned short* dst = &Vs[bsel][0] + w * 512;
    #pragma unroll
    for (int i = 0; i < 4; ++i)
      gload16(vsrc0 + (size_t)(i * 32) * S_LEN + kvn, dst + i * 2048);
  };
  auto loadK = [&](int kvn) {
    const unsigned short* kf = kf0 + (size_t)kvn * DH;
    #pragma unroll
    for (int j = 0; j < 4; ++j)
      #pragma unroll
      for (int kk = 0; kk < 4; ++kk)
        kreg[j * 4 + kk] = *(const bf16x8*)(kf + (size_t)(j * 16) * DH + kk * 32);
  };

  int buf = 0;
  loadV(0, 0);
  loadK(0);
  asm volatile("s_waitcnt vmcnt(16)" ::: "memory");  // drain V DMA, keep K in flight
  __builtin_amdgcn_s_barrier();

  bf16x8 ones;
  #pragma unroll
  for (int c = 0; c < 8; ++c) ones[c] = (__bf16)1.0f;

  #pragma unroll 1
  for (int pass = 0; pass < 2; ++pass) {
    const int qt = pass ? (int)blockIdx.x : 31 - (int)blockIdx.x;
    const int Q0 = qt * 64;
    const unsigned short* Qp = Qh + ((size_t)(b * NH + h) * S_LEN + Q0) * DH;
    bf16x8 qfr[4];
    #pragma unroll
    for (int kk = 0; kk < 4; ++kk)
      qfr[kk] = *(const bf16x8*)(Qp + (size_t)(w * 16 + lm) * DH + kk * 32 + gq * 8);

    floatx4 acc_o[8] = {};
    floatx4 acc_l = {};

    #pragma unroll 1
    for (int it = 0; it <= qt; ++it) {
      const int kv0 = it * 64;
      const int kvn = (it < qt) ? kv0 + 64 : 0;  // next tile (or next pass's tile 0)
      // issue next-tile V DMA into the other buffer (its last readers finished
      // before the previous iteration's end barrier)
      loadV(kvn, buf ^ 1);
      // S = Q K^T from registers (rows=q, cols=kv)
      floatx4 sa[4] = {};
      #pragma unroll
      for (int j = 0; j < 4; ++j)
        #pragma unroll
        for (int kk = 0; kk < 4; ++kk)
          sa[j] = __builtin_amdgcn_mfma_f32_16x16x32_bf16(qfr[kk], kreg[j * 4 + kk], sa[j], 0, 0, 0);
      // kreg consumed -> issue next-tile K fragment loads (covered by exp+PV+barrier)
      loadK(kvn);
      // masked exp -> Ps (per-wave private; same-wave ordering only)
      const int rowb = Q0 + w * 16 + gq * 4;
      #pragma unroll
      for (int r = 0; r < 4; ++r) {
        const int qg = rowb + r;
        #pragma unroll
        for (int j = 0; j < 4; ++j) {
          const int kg = kv0 + j * 16 + lm;
          const float p = (kg <= qg) ? __expf(sa[j][r]) : 0.0f;
          Ps[w][gq * 4 + r][j * 16 + lm] = __builtin_bit_cast(unsigned short, (__bf16)p);
        }
      }
      // P V swapped: op1=V (rows=d, XOR-swizzled cols), op2=P -> regs along d
      bf16x8 ap0 = *(const bf16x8*)&Ps[w][lm][gq * 8];
      bf16x8 ap1 = *(const bf16x8*)&Ps[w][lm][32 + gq * 8];
      const unsigned short* Vb = &Vs[buf][0];
      const int sw0 = (gq ^ (lm & 7)) * 8;
      const int sw1 = ((4 | gq) ^ (lm & 7)) * 8;
      #pragma unroll
      for (int jd = 0; jd < 8; ++jd) {
        const int row = (jd * 16 + lm) * 64;
        bf16x8 bv0 = *(const bf16x8*)&Vb[row + sw0];
        bf16x8 bv1 = *(const bf16x8*)&Vb[row + sw1];
        acc_o[jd] = __builtin_amdgcn_mfma_f32_16x16x32_bf16(bv0, ap0, acc_o[jd], 0, 0, 0);
        acc_o[jd] = __builtin_amdgcn_mfma_f32_16x16x32_bf16(bv1, ap1, acc_o[jd], 0, 0, 0);
      }
      acc_l = __builtin_amdgcn_mfma_f32_16x16x32_bf16(ones, ap0, acc_l, 0, 0, 0);
      acc_l = __builtin_amdgcn_mfma_f32_16x16x32_bf16(ones, ap1, acc_l, 0, 0, 0);
      // drain this iter's 4 V-DMAs (oldest; 16 K-loads stay in flight) and my
      // LDS reads, then barrier: next iter may overwrite Vs[buf].
      asm volatile("s_waitcnt vmcnt(16) lgkmcnt(0)" ::: "memory");
      __builtin_amdgcn_s_barrier();
      buf ^= 1;
    }

    const float inv = 1.0f / acc_l[0];  // all 4 regs equal (row-sum per col s=lm)
    const size_t t_ = (size_t)b * S_LEN + Q0 + w * 16 + lm;
    #pragma unroll
    for (int jd = 0; jd < 8; ++jd) {
      ushortx4 pk;
      #pragma unroll
      for (int r = 0; r < 4; ++r) pk[r] = f2bf(acc_o[jd][r] * inv);
      *(ushortx4*)&Z[t_ * (NH * DH) + h * DH + jd * 16 + gq * 4] = pk;
    }
  }
}

extern "C" void kernel_launch(void* const* d_in, const int* in_sizes, int n_in,
                              void* d_out, int out_size, void* d_ws, size_t ws_size,
                              hipStream_t stream) {
  (void)in_sizes; (void)n_in; (void)out_size; (void)ws_size;
  const float* q  = (const float*)d_in[0];
  const float* k  = (const float*)d_in[1];
  const float* v  = (const float*)d_in[2];
  const float* Wq = (const float*)d_in[3];
  const float* Wk = (const float*)d_in[4];
  const float* Wv = (const float*)d_in[5];
  const float* Wo = (const float*)d_in[6];

  unsigned short* Qh  = (unsigned short*)d_ws;
  unsigned short* Kh  = Qh + (size_t)2 * NH * S_LEN * DH;
  unsigned short* Vt  = Kh + (size_t)2 * KVH * S_LEN * DH;
  unsigned short* Z   = Vt + (size_t)2 * KVH * S_LEN * DH;
  unsigned short* vb  = Z + (size_t)4096 * 2048;
  unsigned short* Wqt = vb + (size_t)4096 * 2048;
  unsigned short* Wkt = Wqt + (size_t)2048 * 2048;
  unsigned short* Wvt = Wkt + (size_t)512 * 2048;
  unsigned short* Wot = Wvt + (size_t)512 * 2048;
  // qb/kb live in d_out (dead before out_kernel writes d_out)
  unsigned short* qb = (unsigned short*)d_out;
  unsigned short* kb = qb + (size_t)4096 * 2048;

  const float scale = 0.29730177875068026f;  // 128^(-1/4), folded into Wq/Wk

  static int s_attr_done = 0;
  if (!s_attr_done) {
    hipFuncSetAttribute(reinterpret_cast<const void*>(proj_kernel),
                        hipFuncAttributeMaxDynamicSharedMemorySize, 131072);
    hipFuncSetAttribute(reinterpret_cast<const void*>(out_kernel),
                        hipFuncAttributeMaxDynamicSharedMemorySize, 131072);
    s_attr_done = 1;
  }

  pre_kernel<<<22528, 256, 0, stream>>>(q, k, v, Wq, Wk, Wv, Wo,
                                        qb, kb, vb, Wqt, Wkt, Wvt, Wot, scale);
  proj_kernel<<<192, 512, 131072, stream>>>(qb, kb, vb, Wqt, Wkt, Wvt, Qh, Kh, Vt);
  attn_kernel<<<dim3(16, 16, 2), 256, 0, stream>>>(Qh, Kh, Vt, Z);
  out_kernel<<<128, 512, 131072, stream>>>(Z, Wot, (float*)d_out);
}

// Round 4
// 348.102 us; speedup vs baseline: 1.1966x; 1.1966x over previous
//
#include <hip/hip_runtime.h>

#define S_LEN 2048
#define EMB 2048
#define NH 16
#define KVH 4
#define DH 128

typedef __bf16 bf16x8 __attribute__((ext_vector_type(8)));
typedef float floatx4 __attribute__((ext_vector_type(4)));
typedef unsigned short ushortx8 __attribute__((ext_vector_type(8)));
typedef unsigned short ushortx4 __attribute__((ext_vector_type(4)));

static __device__ __forceinline__ unsigned short f2bf(float f) {
  unsigned u = __float_as_uint(f);
  return (unsigned short)((u + 0x7fffu + ((u >> 16) & 1u)) >> 16);
}

// async 16B global -> LDS (wave-uniform LDS base + lane*16)
static __device__ __forceinline__ void gload16(const unsigned short* g, unsigned short* l) {
  __builtin_amdgcn_global_load_lds(
      (const __attribute__((address_space(1))) unsigned int*)(const void*)g,
      (__attribute__((address_space(3))) unsigned int*)(void*)l, 16, 0, 0);
}

// ---- fused preprocessing: qkv fp32->bf16 (blocks 0..12287) + weight
// ---- transpose/scale/convert to [N][K] bf16 (blocks 12288..22527)
__global__ __launch_bounds__(256) void pre_kernel(
    const float* __restrict__ q, const float* __restrict__ k, const float* __restrict__ v,
    const float* __restrict__ Wq, const float* __restrict__ Wk,
    const float* __restrict__ Wv, const float* __restrict__ Wo,
    unsigned short* __restrict__ qo, unsigned short* __restrict__ ko,
    unsigned short* __restrict__ vo,
    unsigned short* __restrict__ Wqt, unsigned short* __restrict__ Wkt,
    unsigned short* __restrict__ Wvt, unsigned short* __restrict__ Wot,
    float scale) {
  __shared__ float t[32][33];
  int bx = blockIdx.x;
  if (bx < 12288) {
    const int sel = bx >> 12;
    const float* in = (sel == 0) ? q : (sel == 1) ? k : v;
    unsigned short* out = (sel == 0) ? qo : (sel == 1) ? ko : vo;
    size_t i = (((size_t)(bx & 4095)) * 256 + threadIdx.x) * 8;
    floatx4 a = *(const floatx4*)(in + i);
    floatx4 bvec = *(const floatx4*)(in + i + 4);
    ushortx8 o;
    #pragma unroll
    for (int c = 0; c < 4; ++c) { o[c] = f2bf(a[c]); o[4 + c] = f2bf(bvec[c]); }
    *(ushortx8*)(out + i) = o;
  } else {
    bx -= 12288;
    const float* W; unsigned short* Wt; int N, tile; float sc;
    if (bx < 4096)      { W = Wq; Wt = Wqt; N = 2048; tile = bx;        sc = scale; }
    else if (bx < 5120) { W = Wk; Wt = Wkt; N = 512;  tile = bx - 4096; sc = scale; }
    else if (bx < 6144) { W = Wv; Wt = Wvt; N = 512;  tile = bx - 5120; sc = 1.0f; }
    else                { W = Wo; Wt = Wot; N = 2048; tile = bx - 6144; sc = 1.0f; }
    const int ntiles = N >> 5;
    const int n0 = (tile % ntiles) * 32, k0 = (tile / ntiles) * 32;
    const int tx = threadIdx.x & 31, ty = threadIdx.x >> 5;
    #pragma unroll
    for (int r = 0; r < 4; ++r)
      t[ty + r * 8][tx] = W[(size_t)(k0 + ty + r * 8) * N + n0 + tx];
    __syncthreads();
    #pragma unroll
    for (int r = 0; r < 4; ++r)
      Wt[(size_t)(n0 + ty + r * 8) * 2048 + k0 + tx] = f2bf(t[tx][ty + r * 8] * sc);
  }
}

// ================= 256x256 / BK=64 / 8-wave / 8-phase GEMM core =================
// (unchanged from the 355.8us build; see schedule comment in R1/R2)
static __device__ __forceinline__ void gemm256_core(
    const unsigned short* __restrict__ Ab, const unsigned short* __restrict__ Bb,
    bool swap, unsigned short* As, unsigned short* Bs, floatx4 (&acc)[8][4]) {
  const int tid = threadIdx.x;
  const int lane = tid & 63, w = tid >> 6;
  const int lm = lane & 15, gq = lane >> 4;
  const int wm = w >> 2, wn = w & 3;
  const int lr = lane >> 3, lc = (lane & 7) ^ lr;

  auto stageH = [&](const unsigned short* gb, unsigned short* lt, int half, int kst) {
    #pragma unroll
    for (int qq = 0; qq < 2; ++qq) {
      const int rb = half * 128 + w * 16 + qq * 8;
      gload16(gb + (((size_t)(rb + lr)) << 11) + kst + (lc << 3), lt + rb * 64);
    }
  };

  unsigned short* As2 = As + 16384;
  unsigned short* Bs2 = Bs + 16384;

  // prologue: tile0 (all 4 halves) -> buf0; A(1)h0 -> buf1
  stageH(Ab, As, 0, 0);  stageH(Ab, As, 1, 0);
  stageH(Bb, Bs, 0, 0);  stageH(Bb, Bs, 1, 0);
  stageH(Ab, As2, 0, 64);
  asm volatile("s_waitcnt vmcnt(2)" ::: "memory");
  __builtin_amdgcn_s_barrier();

  const int r1 = (wm * 128 + lm) * 64;             // op1 row base (frag i: +i*1024)
  const int r2 = (wn * 64 + lm) * 64;              // op2 row base (frag j: +j*1024)
  const int c0 = ((0 + gq) ^ (lm & 7)) * 8;        // kk0 chunk (XOR-swizzled)
  const int c1 = ((4 + gq) ^ (lm & 7)) * 8;        // kk1 chunk

#define TILE_BODY(CA, CB, OA, OB, KS1, KS2, STG1, STG4)                                         \
  {                                                                                             \
    const unsigned short* l1 = swap ? (CB) : (CA);                                              \
    const unsigned short* l2 = swap ? (CA) : (CB);                                              \
    bf16x8 op1[8], o2a[4], o2b[4];                                                              \
    _Pragma("unroll") for (int i = 0; i < 8; ++i)                                               \
      op1[i] = *(const bf16x8*)&l1[r1 + i * 1024 + c0];                                         \
    _Pragma("unroll") for (int j = 0; j < 4; ++j)                                               \
      o2a[j] = *(const bf16x8*)&l2[r2 + j * 1024 + c0];                                         \
    if (STG1) stageH(Ab, (OA), 1, (KS1));                                                       \
    __builtin_amdgcn_s_barrier();                                                               \
    asm volatile("s_waitcnt lgkmcnt(0)" ::: "memory");                                          \
    __builtin_amdgcn_s_setprio(1);                                                              \
    _Pragma("unroll") for (int i = 0; i < 8; ++i) {                                             \
      acc[i][0] = __builtin_amdgcn_mfma_f32_16x16x32_bf16(op1[i], o2a[0], acc[i][0], 0, 0, 0);  \
      acc[i][1] = __builtin_amdgcn_mfma_f32_16x16x32_bf16(op1[i], o2a[1], acc[i][1], 0, 0, 0);  \
    }                                                                                           \
    __builtin_amdgcn_s_setprio(0);                                                              \
    __builtin_amdgcn_s_barrier();                                                               \
    _Pragma("unroll") for (int j = 0; j < 4; ++j)                                               \
      o2b[j] = *(const bf16x8*)&l2[r2 + j * 1024 + c1];                                         \
    if (STG1) stageH(Bb, (OB), 0, (KS1));                                                       \
    __builtin_amdgcn_s_barrier();                                                               \
    asm volatile("s_waitcnt lgkmcnt(0)" ::: "memory");                                          \
    __builtin_amdgcn_s_setprio(1);                                                              \
    _Pragma("unroll") for (int i = 0; i < 8; ++i) {                                             \
      acc[i][2] = __builtin_amdgcn_mfma_f32_16x16x32_bf16(op1[i], o2a[2], acc[i][2], 0, 0, 0);  \
      acc[i][3] = __builtin_amdgcn_mfma_f32_16x16x32_bf16(op1[i], o2a[3], acc[i][3], 0, 0, 0);  \
    }                                                                                           \
    __builtin_amdgcn_s_setprio(0);                                                              \
    __builtin_amdgcn_s_barrier();                                                               \
    _Pragma("unroll") for (int i = 0; i < 8; ++i)                                               \
      op1[i] = *(const bf16x8*)&l1[r1 + i * 1024 + c1];                                         \
    if (STG1) stageH(Bb, (OB), 1, (KS1));                                                       \
    __builtin_amdgcn_s_barrier();                                                               \
    asm volatile("s_waitcnt lgkmcnt(0)" ::: "memory");                                          \
    __builtin_amdgcn_s_setprio(1);                                                              \
    _Pragma("unroll") for (int i = 0; i < 8; ++i) {                                             \
      acc[i][0] = __builtin_amdgcn_mfma_f32_16x16x32_bf16(op1[i], o2b[0], acc[i][0], 0, 0, 0);  \
      acc[i][1] = __builtin_amdgcn_mfma_f32_16x16x32_bf16(op1[i], o2b[1], acc[i][1], 0, 0, 0);  \
    }                                                                                           \
    __builtin_amdgcn_s_setprio(0);                                                              \
    __builtin_amdgcn_s_barrier();                                                               \
    if (STG4) stageH(Ab, (CA), 0, (KS2));                                                       \
    __builtin_amdgcn_s_barrier();                                                               \
    __builtin_amdgcn_s_setprio(1);                                                              \
    _Pragma("unroll") for (int i = 0; i < 8; ++i) {                                             \
      acc[i][2] = __builtin_amdgcn_mfma_f32_16x16x32_bf16(op1[i], o2b[2], acc[i][2], 0, 0, 0);  \
      acc[i][3] = __builtin_amdgcn_mfma_f32_16x16x32_bf16(op1[i], o2b[3], acc[i][3], 0, 0, 0);  \
    }                                                                                           \
    __builtin_amdgcn_s_setprio(0);                                                              \
    if (STG4) { asm volatile("s_waitcnt vmcnt(2)" ::: "memory"); }                              \
    else      { asm volatile("s_waitcnt vmcnt(0)" ::: "memory"); }                              \
    __builtin_amdgcn_s_barrier();                                                               \
  }

  #pragma unroll 1
  for (int t = 0; t < 30; t += 2) {
    TILE_BODY(As, Bs, As2, Bs2, (t + 1) * 64, (t + 2) * 64, 1, 1);
    TILE_BODY(As2, Bs2, As, Bs, (t + 2) * 64, (t + 3) * 64, 1, 1);
  }
  TILE_BODY(As, Bs, As2, Bs2, 31 * 64, 0, 1, 0);
  TILE_BODY(As2, Bs2, As, Bs, 0, 0, 0, 0);
#undef TILE_BODY
}

// ---- merged Q/K/V projection GEMM: 192 blocks of 256x256, K=2048 ----
__global__ __launch_bounds__(512, 2) void proj_kernel(
    const unsigned short* __restrict__ qb, const unsigned short* __restrict__ kb,
    const unsigned short* __restrict__ vb,
    const unsigned short* __restrict__ Wqt, const unsigned short* __restrict__ Wkt,
    const unsigned short* __restrict__ Wvt,
    unsigned short* __restrict__ Qh, unsigned short* __restrict__ Kh,
    unsigned short* __restrict__ Vt) {
  extern __shared__ unsigned short lds[];
  unsigned short* As = lds;            // 2 x 16384
  unsigned short* Bs = lds + 32768;    // 2 x 16384
  int bid = (int)blockIdx.x;
  bid = (bid & 7) * 24 + (bid >> 3);   // XCD swizzle (192 % 8 == 0 -> bijective)
  const unsigned short *Ab, *Bb;
  int task, bn, bt;
  if (bid < 128)      { task = 0; bn = bid >> 4;         bt = bid & 15;         Ab = qb; Bb = Wqt; }
  else if (bid < 160) { task = 1; bn = (bid - 128) >> 4; bt = (bid - 128) & 15; Ab = kb; Bb = Wkt; }
  else                { task = 2; bn = (bid - 160) >> 4; bt = (bid - 160) & 15; Ab = vb; Bb = Wvt; }
  Ab += ((size_t)bt) << 19;   // bt*256*2048
  Bb += ((size_t)bn) << 19;

  floatx4 acc[8][4] = {};
  gemm256_core(Ab, Bb, task != 2, As, Bs, acc);

  const int tid = threadIdx.x, lane = tid & 63, w = tid >> 6;
  const int lm = lane & 15, gq = lane >> 4;
  const int wm = w >> 2, wn = w & 3;
  if (task != 2) {           // Q/K: rows=d (weight n-dim), cols=t
    unsigned short* outp = (task == 0) ? Qh : Kh;
    const int nheads = (task == 0) ? NH : KVH;
    const int head = bn * 2 + wm;
    #pragma unroll
    for (int i = 0; i < 8; ++i) {
      const int d0 = i * 16 + gq * 4;
      #pragma unroll
      for (int j = 0; j < 4; ++j) {
        const int tg = bt * 256 + wn * 64 + j * 16 + lm;
        const int b_ = tg >> 11, s_ = tg & 2047;
        ushortx4 pk;
        #pragma unroll
        for (int r = 0; r < 4; ++r) pk[r] = f2bf(acc[i][j][r]);
        *(ushortx4*)&outp[((size_t)(b_ * nheads + head) * S_LEN + s_) * DH + d0] = pk;
      }
    }
  } else {                   // V: rows=s, cols=d -> Vt [B,KVH,D,S]
    #pragma unroll
    for (int i = 0; i < 8; ++i) {
      const int sgl = bt * 256 + wm * 128 + i * 16 + gq * 4;
      const int b_ = sgl >> 11, s_ = sgl & 2047;
      #pragma unroll
      for (int j = 0; j < 4; ++j) {
        const int dl = wn * 64 + j * 16;
        const int head = bn * 2 + (dl >> 7);
        const int dd = (dl & 127) + lm;
        ushortx4 pk;
        #pragma unroll
        for (int r = 0; r < 4; ++r) pk[r] = f2bf(acc[i][j][r]);
        *(ushortx4*)&Vt[((size_t)(b_ * KVH + head) * DH + dd) * S_LEN + s_] = pk;
      }
    }
  }
}

// ---- final GEMM: out[t][n] fp32 = Z[t][k] * Wot[n][k]^T, 128 blocks 256x256 ----
__global__ __launch_bounds__(512, 2) void out_kernel(const unsigned short* __restrict__ Z,
                                                     const unsigned short* __restrict__ Wot,
                                                     float* __restrict__ outp) {
  extern __shared__ unsigned short lds[];
  unsigned short* As = lds;
  unsigned short* Bs = lds + 32768;
  int bid = (int)blockIdx.x;
  bid = (bid & 7) * 16 + (bid >> 3);   // XCD swizzle (128 % 8 == 0)
  const int bn = bid >> 4, bt = bid & 15;

  floatx4 acc[8][4] = {};
  gemm256_core(Z + (((size_t)bt) << 19), Wot + (((size_t)bn) << 19), true, As, Bs, acc);

  const int tid = threadIdx.x, lane = tid & 63, w = tid >> 6;
  const int lm = lane & 15, gq = lane >> 4;
  const int wm = w >> 2, wn = w & 3;
  #pragma unroll
  for (int i = 0; i < 8; ++i) {
    const int n0 = bn * 256 + wm * 128 + i * 16 + gq * 4;
    #pragma unroll
    for (int j = 0; j < 4; ++j) {
      const int tg = bt * 256 + wn * 64 + j * 16 + lm;
      *(floatx4*)&outp[(size_t)tg * 2048 + n0] = acc[i][j];
    }
  }
}

// ---- flash-style causal attention, wave-level 2x reuse:
// q-tile = 128 rows/block (32/wave, 2 row-groups of 16), kv-tile = 64.
// K and V both DMA-staged (global_load_lds) into linear double buffers with
// source-side XOR chunk swizzle; reads apply the same XOR -> conflict-free
// b128 reads, ZERO ds_write instructions for K/V. Each wave's 16 K-reads +
// 16 V-reads now feed 2x the MFMAs (halved LDS volume per unit work).
// Prefetch DMA issues at iter start into the other buffer; drained by
// vmcnt(0)+barrier at iter end (latency covered by the compute phase).
// Grid (8,16,2): pass0 qt=15-bx, pass1 qt=bx -> uniform 36 iters/block.
__global__ __launch_bounds__(256, 1) void attn_kernel(const unsigned short* __restrict__ Qh,
                                                      const unsigned short* __restrict__ Kh,
                                                      const unsigned short* __restrict__ Vt,
                                                      unsigned short* __restrict__ Z) {
  extern __shared__ unsigned short alds[];
  unsigned short* KsB = alds;            // 2 x [64][128] = 2 x 8192
  unsigned short* VsB = alds + 16384;    // 2 x [128][64] = 2 x 8192
  unsigned short* PsB = alds + 32768;    // 4 waves x [32][88]
  const int tid = threadIdx.x;
  const int w = tid >> 6, lane = tid & 63;
  const int lm = lane & 15, gq = lane >> 4;
  const int h = blockIdx.y, b = blockIdx.z;
  const unsigned short* Kp = Kh + (size_t)(b * KVH + (h >> 2)) * S_LEN * DH;
  const unsigned short* Vp = Vt + (size_t)(b * KVH + (h >> 2)) * DH * S_LEN;
  unsigned short* psW = PsB + w * (32 * 88);

  // K DMA: chunk n = w*256+i*64+lane -> r = w*16+i*4+(lane>>4), c = lane&15;
  // src col chunk = c ^ (r&7); (r&7) = (lane>>4) + 4*(i&1) since w*16,8|i*4 cancel mod 8
  const int krr = w * 16 + (lane >> 4);
  const int kcE = ((lane & 15) ^ (lane >> 4)) * 8;
  const int kcO = ((lane & 15) ^ ((lane >> 4) | 4)) * 8;
  auto loadK = [&](int kv, unsigned short* dstbuf) {
    #pragma unroll
    for (int i = 0; i < 4; ++i)
      gload16(Kp + (size_t)(kv + krr + i * 4) * DH + ((i & 1) ? kcO : kcE),
              dstbuf + w * 2048 + i * 512);
  };
  // V DMA (R3-proven): chunk n = i*256+w*64+lane -> d = i*32+(tid>>3), c = tid&7;
  // src col chunk = c ^ (d&7)
  const int vrow8 = tid >> 3;
  const int vsig = (tid & 7) ^ (vrow8 & 7);
  const unsigned short* vsrc0 = Vp + (size_t)vrow8 * S_LEN + vsig * 8;
  auto loadV = [&](int kv, unsigned short* dstbuf) {
    unsigned short* dst = dstbuf + w * 512;
    #pragma unroll
    for (int i = 0; i < 4; ++i)
      gload16(vsrc0 + (size_t)(i * 32) * S_LEN + kv, dst + i * 2048);
  };

  // read-side swizzled chunk offsets
  int kcol[4];
  #pragma unroll
  for (int kk = 0; kk < 4; ++kk) kcol[kk] = ((kk * 4 + gq) ^ (lm & 7)) * 8;
  const int sw0 = (gq ^ (lm & 7)) * 8;
  const int sw1 = ((4 | gq) ^ (lm & 7)) * 8;

  bf16x8 ones;
  #pragma unroll
  for (int c = 0; c < 8; ++c) ones[c] = (__bf16)1.0f;

  // prologue: tile 0 -> buf 0
  loadK(0, KsB);
  loadV(0, VsB);
  asm volatile("s_waitcnt vmcnt(0)" ::: "memory");
  __builtin_amdgcn_s_barrier();
  int buf = 0;

  #pragma unroll 1
  for (int pass = 0; pass < 2; ++pass) {
    const int qt = pass ? (int)blockIdx.x : 15 - (int)blockIdx.x;
    const int Q0 = qt * 128;
    const int nit = 2 * qt + 2;
    const unsigned short* Qp = Qh + ((size_t)(b * NH + h) * S_LEN + Q0) * DH;
    bf16x8 qfr[2][4];
    #pragma unroll
    for (int g = 0; g < 2; ++g)
      #pragma unroll
      for (int kk = 0; kk < 4; ++kk)
        qfr[g][kk] = *(const bf16x8*)(Qp + (size_t)(w * 32 + g * 16 + lm) * DH + kk * 32 + gq * 8);

    floatx4 acc_o[2][8] = {};
    floatx4 acc_l[2] = {};

    #pragma unroll 1
    for (int it = 0; it < nit; ++it) {
      const int kv0 = it * 64;
      const unsigned short* Kc = KsB + buf * 8192;
      const unsigned short* Vc = VsB + buf * 8192;
      // prefetch next tile (or next pass's tile 0) into the other buffer
      if (!(pass == 1 && it == nit - 1)) {
        const int kvn = (it + 1 < nit) ? kv0 + 64 : 0;
        loadK(kvn, KsB + (buf ^ 1) * 8192);
        loadV(kvn, VsB + (buf ^ 1) * 8192);
      }
      // S = Q K^T : K fragments from LDS, reused by both row-groups
      bf16x8 kreg[4][4];
      #pragma unroll
      for (int j = 0; j < 4; ++j)
        #pragma unroll
        for (int kk = 0; kk < 4; ++kk)
          kreg[j][kk] = *(const bf16x8*)&Kc[(j * 16 + lm) * 128 + kcol[kk]];
      floatx4 sa[2][4] = {};
      #pragma unroll
      for (int g = 0; g < 2; ++g)
        #pragma unroll
        for (int j = 0; j < 4; ++j)
          #pragma unroll
          for (int kk = 0; kk < 4; ++kk)
            sa[g][j] = __builtin_amdgcn_mfma_f32_16x16x32_bf16(qfr[g][kk], kreg[j][kk], sa[g][j], 0, 0, 0);
      // masked exp -> Ps (per-wave private; same-wave ordering only)
      #pragma unroll
      for (int g = 0; g < 2; ++g) {
        const int rowb = Q0 + w * 32 + g * 16 + gq * 4;
        #pragma unroll
        for (int r = 0; r < 4; ++r) {
          const int qg = rowb + r;
          #pragma unroll
          for (int j = 0; j < 4; ++j) {
            const int kg = kv0 + j * 16 + lm;
            const float p = (kg <= qg) ? __expf(sa[g][j][r]) : 0.0f;
            psW[(g * 16 + gq * 4 + r) * 88 + j * 16 + lm] = __builtin_bit_cast(unsigned short, (__bf16)p);
          }
        }
      }
      // P V swapped: op1=V (rows=d, XOR-swizzled cols), op2=P -> regs along d.
      // V reads shared by both row-groups.
      bf16x8 ap[2][2];
      #pragma unroll
      for (int g = 0; g < 2; ++g) {
        ap[g][0] = *(const bf16x8*)&psW[(g * 16 + lm) * 88 + gq * 8];
        ap[g][1] = *(const bf16x8*)&psW[(g * 16 + lm) * 88 + 32 + gq * 8];
      }
      #pragma unroll
      for (int jd = 0; jd < 8; ++jd) {
        const int row = (jd * 16 + lm) * 64;
        bf16x8 bv0 = *(const bf16x8*)&Vc[row + sw0];
        bf16x8 bv1 = *(const bf16x8*)&Vc[row + sw1];
        #pragma unroll
        for (int g = 0; g < 2; ++g) {
          acc_o[g][jd] = __builtin_amdgcn_mfma_f32_16x16x32_bf16(bv0, ap[g][0], acc_o[g][jd], 0, 0, 0);
          acc_o[g][jd] = __builtin_amdgcn_mfma_f32_16x16x32_bf16(bv1, ap[g][1], acc_o[g][jd], 0, 0, 0);
        }
      }
      #pragma unroll
      for (int g = 0; g < 2; ++g) {
        acc_l[g] = __builtin_amdgcn_mfma_f32_16x16x32_bf16(ones, ap[g][0], acc_l[g], 0, 0, 0);
        acc_l[g] = __builtin_amdgcn_mfma_f32_16x16x32_bf16(ones, ap[g][1], acc_l[g], 0, 0, 0);
      }
      // drain prefetch DMA + my LDS ops, then barrier: buffers may be swapped.
      asm volatile("s_waitcnt vmcnt(0) lgkmcnt(0)" ::: "memory");
      __builtin_amdgcn_s_barrier();
      buf ^= 1;
    }

    #pragma unroll
    for (int g = 0; g < 2; ++g) {
      const float inv = 1.0f / acc_l[g][0];  // all 4 regs equal
      const size_t t_ = (size_t)b * S_LEN + Q0 + w * 32 + g * 16 + lm;
      #pragma unroll
      for (int jd = 0; jd < 8; ++jd) {
        ushortx4 pk;
        #pragma unroll
        for (int r = 0; r < 4; ++r) pk[r] = f2bf(acc_o[g][jd][r] * inv);
        *(ushortx4*)&Z[t_ * (NH * DH) + h * DH + jd * 16 + gq * 4] = pk;
      }
    }
  }
}

extern "C" void kernel_launch(void* const* d_in, const int* in_sizes, int n_in,
                              void* d_out, int out_size, void* d_ws, size_t ws_size,
                              hipStream_t stream) {
  (void)in_sizes; (void)n_in; (void)out_size; (void)ws_size;
  const float* q  = (const float*)d_in[0];
  const float* k  = (const float*)d_in[1];
  const float* v  = (const float*)d_in[2];
  const float* Wq = (const float*)d_in[3];
  const float* Wk = (const float*)d_in[4];
  const float* Wv = (const float*)d_in[5];
  const float* Wo = (const float*)d_in[6];

  unsigned short* Qh  = (unsigned short*)d_ws;
  unsigned short* Kh  = Qh + (size_t)2 * NH * S_LEN * DH;
  unsigned short* Vt  = Kh + (size_t)2 * KVH * S_LEN * DH;
  unsigned short* Z   = Vt + (size_t)2 * KVH * S_LEN * DH;
  unsigned short* vb  = Z + (size_t)4096 * 2048;
  unsigned short* Wqt = vb + (size_t)4096 * 2048;
  unsigned short* Wkt = Wqt + (size_t)2048 * 2048;
  unsigned short* Wvt = Wkt + (size_t)512 * 2048;
  unsigned short* Wot = Wvt + (size_t)512 * 2048;
  // qb/kb live in d_out (dead before out_kernel writes d_out)
  unsigned short* qb = (unsigned short*)d_out;
  unsigned short* kb = qb + (size_t)4096 * 2048;

  const float scale = 0.29730177875068026f;  // 128^(-1/4), folded into Wq/Wk

  static int s_attr_done = 0;
  if (!s_attr_done) {
    hipFuncSetAttribute(reinterpret_cast<const void*>(proj_kernel),
                        hipFuncAttributeMaxDynamicSharedMemorySize, 131072);
    hipFuncSetAttribute(reinterpret_cast<const void*>(out_kernel),
                        hipFuncAttributeMaxDynamicSharedMemorySize, 131072);
    hipFuncSetAttribute(reinterpret_cast<const void*>(attn_kernel),
                        hipFuncAttributeMaxDynamicSharedMemorySize, 90112);
    s_attr_done = 1;
  }

  pre_kernel<<<22528, 256, 0, stream>>>(q, k, v, Wq, Wk, Wv, Wo,
                                        qb, kb, vb, Wqt, Wkt, Wvt, Wot, scale);
  proj_kernel<<<192, 512, 131072, stream>>>(qb, kb, vb, Wqt, Wkt, Wvt, Qh, Kh, Vt);
  attn_kernel<<<dim3(8, 16, 2), 256, 88064, stream>>>(Qh, Kh, Vt, Z);
  out_kernel<<<128, 512, 131072, stream>>>(Z, Wot, (float*)d_out);
}

// Round 5
// 347.534 us; speedup vs baseline: 1.1986x; 1.0016x over previous
//
#include <hip/hip_runtime.h>

#define S_LEN 2048
#define EMB 2048
#define NH 16
#define KVH 4
#define DH 128

typedef __bf16 bf16x8 __attribute__((ext_vector_type(8)));
typedef float floatx4 __attribute__((ext_vector_type(4)));
typedef unsigned short ushortx8 __attribute__((ext_vector_type(8)));
typedef unsigned short ushortx4 __attribute__((ext_vector_type(4)));

static __device__ __forceinline__ unsigned short f2bf(float f) {
  unsigned u = __float_as_uint(f);
  return (unsigned short)((u + 0x7fffu + ((u >> 16) & 1u)) >> 16);
}

// async 16B global -> LDS (wave-uniform LDS base + lane*16)
static __device__ __forceinline__ void gload16(const unsigned short* g, unsigned short* l) {
  __builtin_amdgcn_global_load_lds(
      (const __attribute__((address_space(1))) unsigned int*)(const void*)g,
      (__attribute__((address_space(3))) unsigned int*)(void*)l, 16, 0, 0);
}

// ---- fused preprocessing: qkv fp32->bf16 (blocks 0..12287) + weight
// ---- transpose/scale/convert to [N][K] bf16 (blocks 12288..22527)
__global__ __launch_bounds__(256) void pre_kernel(
    const float* __restrict__ q, const float* __restrict__ k, const float* __restrict__ v,
    const float* __restrict__ Wq, const float* __restrict__ Wk,
    const float* __restrict__ Wv, const float* __restrict__ Wo,
    unsigned short* __restrict__ qo, unsigned short* __restrict__ ko,
    unsigned short* __restrict__ vo,
    unsigned short* __restrict__ Wqt, unsigned short* __restrict__ Wkt,
    unsigned short* __restrict__ Wvt, unsigned short* __restrict__ Wot,
    float scale) {
  __shared__ float t[32][33];
  int bx = blockIdx.x;
  if (bx < 12288) {
    const int sel = bx >> 12;
    const float* in = (sel == 0) ? q : (sel == 1) ? k : v;
    unsigned short* out = (sel == 0) ? qo : (sel == 1) ? ko : vo;
    size_t i = (((size_t)(bx & 4095)) * 256 + threadIdx.x) * 8;
    floatx4 a = *(const floatx4*)(in + i);
    floatx4 bvec = *(const floatx4*)(in + i + 4);
    ushortx8 o;
    #pragma unroll
    for (int c = 0; c < 4; ++c) { o[c] = f2bf(a[c]); o[4 + c] = f2bf(bvec[c]); }
    *(ushortx8*)(out + i) = o;
  } else {
    bx -= 12288;
    const float* W; unsigned short* Wt; int N, tile; float sc;
    if (bx < 4096)      { W = Wq; Wt = Wqt; N = 2048; tile = bx;        sc = scale; }
    else if (bx < 5120) { W = Wk; Wt = Wkt; N = 512;  tile = bx - 4096; sc = scale; }
    else if (bx < 6144) { W = Wv; Wt = Wvt; N = 512;  tile = bx - 5120; sc = 1.0f; }
    else                { W = Wo; Wt = Wot; N = 2048; tile = bx - 6144; sc = 1.0f; }
    const int ntiles = N >> 5;
    const int n0 = (tile % ntiles) * 32, k0 = (tile / ntiles) * 32;
    const int tx = threadIdx.x & 31, ty = threadIdx.x >> 5;
    #pragma unroll
    for (int r = 0; r < 4; ++r)
      t[ty + r * 8][tx] = W[(size_t)(k0 + ty + r * 8) * N + n0 + tx];
    __syncthreads();
    #pragma unroll
    for (int r = 0; r < 4; ++r)
      Wt[(size_t)(n0 + ty + r * 8) * 2048 + k0 + tx] = f2bf(t[tx][ty + r * 8] * sc);
  }
}

// ================= 256x256 / BK=64 / 8-wave / 8-phase GEMM core =================
// (unchanged from the 355.8us build; see schedule comment in R1/R2)
static __device__ __forceinline__ void gemm256_core(
    const unsigned short* __restrict__ Ab, const unsigned short* __restrict__ Bb,
    bool swap, unsigned short* As, unsigned short* Bs, floatx4 (&acc)[8][4]) {
  const int tid = threadIdx.x;
  const int lane = tid & 63, w = tid >> 6;
  const int lm = lane & 15, gq = lane >> 4;
  const int wm = w >> 2, wn = w & 3;
  const int lr = lane >> 3, lc = (lane & 7) ^ lr;

  auto stageH = [&](const unsigned short* gb, unsigned short* lt, int half, int kst) {
    #pragma unroll
    for (int qq = 0; qq < 2; ++qq) {
      const int rb = half * 128 + w * 16 + qq * 8;
      gload16(gb + (((size_t)(rb + lr)) << 11) + kst + (lc << 3), lt + rb * 64);
    }
  };

  unsigned short* As2 = As + 16384;
  unsigned short* Bs2 = Bs + 16384;

  // prologue: tile0 (all 4 halves) -> buf0; A(1)h0 -> buf1
  stageH(Ab, As, 0, 0);  stageH(Ab, As, 1, 0);
  stageH(Bb, Bs, 0, 0);  stageH(Bb, Bs, 1, 0);
  stageH(Ab, As2, 0, 64);
  asm volatile("s_waitcnt vmcnt(2)" ::: "memory");
  __builtin_amdgcn_s_barrier();

  const int r1 = (wm * 128 + lm) * 64;             // op1 row base (frag i: +i*1024)
  const int r2 = (wn * 64 + lm) * 64;              // op2 row base (frag j: +j*1024)
  const int c0 = ((0 + gq) ^ (lm & 7)) * 8;        // kk0 chunk (XOR-swizzled)
  const int c1 = ((4 + gq) ^ (lm & 7)) * 8;        // kk1 chunk

#define TILE_BODY(CA, CB, OA, OB, KS1, KS2, STG1, STG4)                                         \
  {                                                                                             \
    const unsigned short* l1 = swap ? (CB) : (CA);                                              \
    const unsigned short* l2 = swap ? (CA) : (CB);                                              \
    bf16x8 op1[8], o2a[4], o2b[4];                                                              \
    _Pragma("unroll") for (int i = 0; i < 8; ++i)                                               \
      op1[i] = *(const bf16x8*)&l1[r1 + i * 1024 + c0];                                         \
    _Pragma("unroll") for (int j = 0; j < 4; ++j)                                               \
      o2a[j] = *(const bf16x8*)&l2[r2 + j * 1024 + c0];                                         \
    if (STG1) stageH(Ab, (OA), 1, (KS1));                                                       \
    __builtin_amdgcn_s_barrier();                                                               \
    asm volatile("s_waitcnt lgkmcnt(0)" ::: "memory");                                          \
    __builtin_amdgcn_s_setprio(1);                                                              \
    _Pragma("unroll") for (int i = 0; i < 8; ++i) {                                             \
      acc[i][0] = __builtin_amdgcn_mfma_f32_16x16x32_bf16(op1[i], o2a[0], acc[i][0], 0, 0, 0);  \
      acc[i][1] = __builtin_amdgcn_mfma_f32_16x16x32_bf16(op1[i], o2a[1], acc[i][1], 0, 0, 0);  \
    }                                                                                           \
    __builtin_amdgcn_s_setprio(0);                                                              \
    __builtin_amdgcn_s_barrier();                                                               \
    _Pragma("unroll") for (int j = 0; j < 4; ++j)                                               \
      o2b[j] = *(const bf16x8*)&l2[r2 + j * 1024 + c1];                                         \
    if (STG1) stageH(Bb, (OB), 0, (KS1));                                                       \
    __builtin_amdgcn_s_barrier();                                                               \
    asm volatile("s_waitcnt lgkmcnt(0)" ::: "memory");                                          \
    __builtin_amdgcn_s_setprio(1);                                                              \
    _Pragma("unroll") for (int i = 0; i < 8; ++i) {                                             \
      acc[i][2] = __builtin_amdgcn_mfma_f32_16x16x32_bf16(op1[i], o2a[2], acc[i][2], 0, 0, 0);  \
      acc[i][3] = __builtin_amdgcn_mfma_f32_16x16x32_bf16(op1[i], o2a[3], acc[i][3], 0, 0, 0);  \
    }                                                                                           \
    __builtin_amdgcn_s_setprio(0);                                                               \
    __builtin_amdgcn_s_barrier();                                                               \
    _Pragma("unroll") for (int i = 0; i < 8; ++i)                                               \
      op1[i] = *(const bf16x8*)&l1[r1 + i * 1024 + c1];                                         \
    if (STG1) stageH(Bb, (OB), 1, (KS1));                                                       \
    __builtin_amdgcn_s_barrier();                                                               \
    asm volatile("s_waitcnt lgkmcnt(0)" ::: "memory");                                          \
    __builtin_amdgcn_s_setprio(1);                                                              \
    _Pragma("unroll") for (int i = 0; i < 8; ++i) {                                             \
      acc[i][0] = __builtin_amdgcn_mfma_f32_16x16x32_bf16(op1[i], o2b[0], acc[i][0], 0, 0, 0);  \
      acc[i][1] = __builtin_amdgcn_mfma_f32_16x16x32_bf16(op1[i], o2b[1], acc[i][1], 0, 0, 0);  \
    }                                                                                           \
    __builtin_amdgcn_s_setprio(0);                                                               \
    __builtin_amdgcn_s_barrier();                                                               \
    if (STG4) stageH(Ab, (CA), 0, (KS2));                                                       \
    __builtin_amdgcn_s_barrier();                                                               \
    __builtin_amdgcn_s_setprio(1);                                                              \
    _Pragma("unroll") for (int i = 0; i < 8; ++i) {                                             \
      acc[i][2] = __builtin_amdgcn_mfma_f32_16x16x32_bf16(op1[i], o2b[2], acc[i][2], 0, 0, 0);  \
      acc[i][3] = __builtin_amdgcn_mfma_f32_16x16x32_bf16(op1[i], o2b[3], acc[i][3], 0, 0, 0);  \
    }                                                                                           \
    __builtin_amdgcn_s_setprio(0);                                                               \
    if (STG4) { asm volatile("s_waitcnt vmcnt(2)" ::: "memory"); }                              \
    else      { asm volatile("s_waitcnt vmcnt(0)" ::: "memory"); }                              \
    __builtin_amdgcn_s_barrier();                                                               \
  }

  #pragma unroll 1
  for (int t = 0; t < 30; t += 2) {
    TILE_BODY(As, Bs, As2, Bs2, (t + 1) * 64, (t + 2) * 64, 1, 1);
    TILE_BODY(As2, Bs2, As, Bs, (t + 2) * 64, (t + 3) * 64, 1, 1);
  }
  TILE_BODY(As, Bs, As2, Bs2, 31 * 64, 0, 1, 0);
  TILE_BODY(As2, Bs2, As, Bs, 0, 0, 0, 0);
#undef TILE_BODY
}

// ---- merged Q/K/V projection GEMM: 192 blocks of 256x256, K=2048 ----
__global__ __launch_bounds__(512, 2) void proj_kernel(
    const unsigned short* __restrict__ qb, const unsigned short* __restrict__ kb,
    const unsigned short* __restrict__ vb,
    const unsigned short* __restrict__ Wqt, const unsigned short* __restrict__ Wkt,
    const unsigned short* __restrict__ Wvt,
    unsigned short* __restrict__ Qh, unsigned short* __restrict__ Kh,
    unsigned short* __restrict__ Vt) {
  extern __shared__ unsigned short lds[];
  unsigned short* As = lds;            // 2 x 16384
  unsigned short* Bs = lds + 32768;    // 2 x 16384
  int bid = (int)blockIdx.x;
  bid = (bid & 7) * 24 + (bid >> 3);   // XCD swizzle (192 % 8 == 0 -> bijective)
  const unsigned short *Ab, *Bb;
  int task, bn, bt;
  if (bid < 128)      { task = 0; bn = bid >> 4;         bt = bid & 15;         Ab = qb; Bb = Wqt; }
  else if (bid < 160) { task = 1; bn = (bid - 128) >> 4; bt = (bid - 128) & 15; Ab = kb; Bb = Wkt; }
  else                { task = 2; bn = (bid - 160) >> 4; bt = (bid - 160) & 15; Ab = vb; Bb = Wvt; }
  Ab += ((size_t)bt) << 19;   // bt*256*2048
  Bb += ((size_t)bn) << 19;

  floatx4 acc[8][4] = {};
  gemm256_core(Ab, Bb, task != 2, As, Bs, acc);

  const int tid = threadIdx.x, lane = tid & 63, w = tid >> 6;
  const int lm = lane & 15, gq = lane >> 4;
  const int wm = w >> 2, wn = w & 3;
  if (task != 2) {           // Q/K: rows=d (weight n-dim), cols=t
    unsigned short* outp = (task == 0) ? Qh : Kh;
    const int nheads = (task == 0) ? NH : KVH;
    const int head = bn * 2 + wm;
    #pragma unroll
    for (int i = 0; i < 8; ++i) {
      const int d0 = i * 16 + gq * 4;
      #pragma unroll
      for (int j = 0; j < 4; ++j) {
        const int tg = bt * 256 + wn * 64 + j * 16 + lm;
        const int b_ = tg >> 11, s_ = tg & 2047;
        ushortx4 pk;
        #pragma unroll
        for (int r = 0; r < 4; ++r) pk[r] = f2bf(acc[i][j][r]);
        *(ushortx4*)&outp[((size_t)(b_ * nheads + head) * S_LEN + s_) * DH + d0] = pk;
      }
    }
  } else {                   // V: rows=s, cols=d -> Vt [B,KVH,D,S]
    #pragma unroll
    for (int i = 0; i < 8; ++i) {
      const int sgl = bt * 256 + wm * 128 + i * 16 + gq * 4;
      const int b_ = sgl >> 11, s_ = sgl & 2047;
      #pragma unroll
      for (int j = 0; j < 4; ++j) {
        const int dl = wn * 64 + j * 16;
        const int head = bn * 2 + (dl >> 7);
        const int dd = (dl & 127) + lm;
        ushortx4 pk;
        #pragma unroll
        for (int r = 0; r < 4; ++r) pk[r] = f2bf(acc[i][j][r]);
        *(ushortx4*)&Vt[((size_t)(b_ * KVH + head) * DH + dd) * S_LEN + s_] = pk;
      }
    }
  }
}

// ---- final GEMM: out[t][n] fp32 = Z[t][k] * Wot[n][k]^T, 128 blocks 256x256 ----
__global__ __launch_bounds__(512, 2) void out_kernel(const unsigned short* __restrict__ Z,
                                                     const unsigned short* __restrict__ Wot,
                                                     float* __restrict__ outp) {
  extern __shared__ unsigned short lds[];
  unsigned short* As = lds;
  unsigned short* Bs = lds + 32768;
  int bid = (int)blockIdx.x;
  bid = (bid & 7) * 16 + (bid >> 3);   // XCD swizzle (128 % 8 == 0)
  const int bn = bid >> 4, bt = bid & 15;

  floatx4 acc[8][4] = {};
  gemm256_core(Z + (((size_t)bt) << 19), Wot + (((size_t)bn) << 19), true, As, Bs, acc);

  const int tid = threadIdx.x, lane = tid & 63, w = tid >> 6;
  const int lm = lane & 15, gq = lane >> 4;
  const int wm = w >> 2, wn = w & 3;
  #pragma unroll
  for (int i = 0; i < 8; ++i) {
    const int n0 = bn * 256 + wm * 128 + i * 16 + gq * 4;
    #pragma unroll
    for (int j = 0; j < 4; ++j) {
      const int tg = bt * 256 + wn * 64 + j * 16 + lm;
      *(floatx4*)&outp[(size_t)tg * 2048 + n0] = acc[i][j];
    }
  }
}

// ---- flash-style causal attention, 2 blocks/CU for SIMD-level TLP:
// q-tile 128/block (32/wave), kv-tile 64. K/V DMA-staged double buffers with
// XOR chunk swizzle (zero ds_writes). Ps: [32][64] pad-free with XOR chunk
// swizzle (chunk' = chunk ^ (row&7)) -> LDS exactly 80 KB -> 2 blocks/CU.
// Grid (16,16,2): qt = b ? 15-bx : bx, so round-robin co-resident pairs
// (bid, bid+256) carry (qt, 15-qt) -> uniform 36 iters per CU. Each block's
// barriers are independent -> one block's vmcnt/barrier stalls are hidden by
// the other block's compute on the same SIMDs.
__global__ __launch_bounds__(256, 2) void attn_kernel(const unsigned short* __restrict__ Qh,
                                                      const unsigned short* __restrict__ Kh,
                                                      const unsigned short* __restrict__ Vt,
                                                      unsigned short* __restrict__ Z) {
  extern __shared__ unsigned short alds[];
  unsigned short* KsB = alds;            // 2 x [64][128] = 32768 B
  unsigned short* VsB = alds + 16384;    // 2 x [128][64] = 32768 B
  unsigned short* PsB = alds + 32768;    // 4 waves x [32][64] swizzled = 16384 B
  const int tid = threadIdx.x;
  const int w = tid >> 6, lane = tid & 63;
  const int lm = lane & 15, gq = lane >> 4;
  const int h = blockIdx.y, b = blockIdx.z;
  const int qt = b ? (15 - (int)blockIdx.x) : (int)blockIdx.x;
  const unsigned short* Kp = Kh + (size_t)(b * KVH + (h >> 2)) * S_LEN * DH;
  const unsigned short* Vp = Vt + (size_t)(b * KVH + (h >> 2)) * DH * S_LEN;
  unsigned short* psW = PsB + w * (32 * 64);

  // K DMA: chunk n = w*256+i*64+lane -> r = w*16+i*4+(lane>>4), c = lane&15;
  // src col chunk = c ^ (r&7); (r&7) = (lane>>4) + 4*(i&1)
  const int krr = w * 16 + (lane >> 4);
  const int kcE = ((lane & 15) ^ (lane >> 4)) * 8;
  const int kcO = ((lane & 15) ^ ((lane >> 4) | 4)) * 8;
  auto loadK = [&](int kv, unsigned short* dstbuf) {
    #pragma unroll
    for (int i = 0; i < 4; ++i)
      gload16(Kp + (size_t)(kv + krr + i * 4) * DH + ((i & 1) ? kcO : kcE),
              dstbuf + w * 2048 + i * 512);
  };
  // V DMA: chunk n = i*256+w*64+lane -> d = i*32+(tid>>3), c = tid&7;
  // src col chunk = c ^ (d&7)
  const int vrow8 = tid >> 3;
  const int vsig = (tid & 7) ^ (vrow8 & 7);
  const unsigned short* vsrc0 = Vp + (size_t)vrow8 * S_LEN + vsig * 8;
  auto loadV = [&](int kv, unsigned short* dstbuf) {
    unsigned short* dst = dstbuf + w * 512;
    #pragma unroll
    for (int i = 0; i < 4; ++i)
      gload16(vsrc0 + (size_t)(i * 32) * S_LEN + kv, dst + i * 2048);
  };

  // read-side swizzled chunk offsets (K/V buffers)
  int kcol[4];
  #pragma unroll
  for (int kk = 0; kk < 4; ++kk) kcol[kk] = ((kk * 4 + gq) ^ (lm & 7)) * 8;
  const int sw0 = (gq ^ (lm & 7)) * 8;
  const int sw1 = ((4 | gq) ^ (lm & 7)) * 8;

  bf16x8 ones;
  #pragma unroll
  for (int c = 0; c < 8; ++c) ones[c] = (__bf16)1.0f;

  const int Q0 = qt * 128;
  const int nit = 2 * qt + 2;
  const unsigned short* Qp = Qh + ((size_t)(b * NH + h) * S_LEN + Q0) * DH;

  // prologue: tile 0 -> buf 0 (Q frag loads counted by the vmcnt(0) too; fine)
  loadK(0, KsB);
  loadV(0, VsB);
  bf16x8 qfr[2][4];
  #pragma unroll
  for (int g = 0; g < 2; ++g)
    #pragma unroll
    for (int kk = 0; kk < 4; ++kk)
      qfr[g][kk] = *(const bf16x8*)(Qp + (size_t)(w * 32 + g * 16 + lm) * DH + kk * 32 + gq * 8);
  asm volatile("s_waitcnt vmcnt(0)" ::: "memory");
  __builtin_amdgcn_s_barrier();
  int buf = 0;

  floatx4 acc_o[2][8] = {};
  floatx4 acc_l[2] = {};

  #pragma unroll 1
  for (int it = 0; it < nit; ++it) {
    const int kv0 = it * 64;
    const unsigned short* Kc = KsB + buf * 8192;
    const unsigned short* Vc = VsB + buf * 8192;
    // prefetch next tile into the other buffer
    if (it + 1 < nit) {
      loadK(kv0 + 64, KsB + (buf ^ 1) * 8192);
      loadV(kv0 + 64, VsB + (buf ^ 1) * 8192);
    }
    // S = Q K^T : K fragments from LDS, reused by both row-groups
    bf16x8 kreg[4][4];
    #pragma unroll
    for (int j = 0; j < 4; ++j)
      #pragma unroll
      for (int kk = 0; kk < 4; ++kk)
        kreg[j][kk] = *(const bf16x8*)&Kc[(j * 16 + lm) * 128 + kcol[kk]];
    floatx4 sa[2][4] = {};
    #pragma unroll
    for (int g = 0; g < 2; ++g)
      #pragma unroll
      for (int j = 0; j < 4; ++j)
        #pragma unroll
        for (int kk = 0; kk < 4; ++kk)
          sa[g][j] = __builtin_amdgcn_mfma_f32_16x16x32_bf16(qfr[g][kk], kreg[j][kk], sa[g][j], 0, 0, 0);
    // masked exp -> Ps (per-wave private; XOR chunk swizzle, pad-free)
    #pragma unroll
    for (int g = 0; g < 2; ++g) {
      const int rowb = Q0 + w * 32 + g * 16 + gq * 4;
      #pragma unroll
      for (int r = 0; r < 4; ++r) {
        const int qg = rowb + r;
        const int prow = g * 16 + gq * 4 + r;
        #pragma unroll
        for (int j = 0; j < 4; ++j) {
          const int kg = kv0 + j * 16 + lm;
          const float p = (kg <= qg) ? __expf(sa[g][j][r]) : 0.0f;
          const int pcol = j * 16 + lm;
          psW[prow * 64 + (((pcol >> 3) ^ (prow & 7)) << 3) + (pcol & 7)] =
              __builtin_bit_cast(unsigned short, (__bf16)p);
        }
      }
    }
    // P V swapped: op1=V (rows=d, XOR-swizzled cols), op2=P -> regs along d.
    bf16x8 ap[2][2];
    #pragma unroll
    for (int g = 0; g < 2; ++g) {
      const int rrow = g * 16 + lm;
      ap[g][0] = *(const bf16x8*)&psW[rrow * 64 + ((gq ^ (rrow & 7)) << 3)];
      ap[g][1] = *(const bf16x8*)&psW[rrow * 64 + (((4 | gq) ^ (rrow & 7)) << 3)];
    }
    #pragma unroll
    for (int jd = 0; jd < 8; ++jd) {
      const int row = (jd * 16 + lm) * 64;
      bf16x8 bv0 = *(const bf16x8*)&Vc[row + sw0];
      bf16x8 bv1 = *(const bf16x8*)&Vc[row + sw1];
      #pragma unroll
      for (int g = 0; g < 2; ++g) {
        acc_o[g][jd] = __builtin_amdgcn_mfma_f32_16x16x32_bf16(bv0, ap[g][0], acc_o[g][jd], 0, 0, 0);
        acc_o[g][jd] = __builtin_amdgcn_mfma_f32_16x16x32_bf16(bv1, ap[g][1], acc_o[g][jd], 0, 0, 0);
      }
    }
    #pragma unroll
    for (int g = 0; g < 2; ++g) {
      acc_l[g] = __builtin_amdgcn_mfma_f32_16x16x32_bf16(ones, ap[g][0], acc_l[g], 0, 0, 0);
      acc_l[g] = __builtin_amdgcn_mfma_f32_16x16x32_bf16(ones, ap[g][1], acc_l[g], 0, 0, 0);
    }
    // drain prefetch DMA + my LDS ops, then barrier: buffers may be swapped.
    asm volatile("s_waitcnt vmcnt(0) lgkmcnt(0)" ::: "memory");
    __builtin_amdgcn_s_barrier();
    buf ^= 1;
  }

  #pragma unroll
  for (int g = 0; g < 2; ++g) {
    const float inv = 1.0f / acc_l[g][0];  // all 4 regs equal
    const size_t t_ = (size_t)b * S_LEN + Q0 + w * 32 + g * 16 + lm;
    #pragma unroll
    for (int jd = 0; jd < 8; ++jd) {
      ushortx4 pk;
      #pragma unroll
      for (int r = 0; r < 4; ++r) pk[r] = f2bf(acc_o[g][jd][r] * inv);
      *(ushortx4*)&Z[t_ * (NH * DH) + h * DH + jd * 16 + gq * 4] = pk;
    }
  }
}

extern "C" void kernel_launch(void* const* d_in, const int* in_sizes, int n_in,
                              void* d_out, int out_size, void* d_ws, size_t ws_size,
                              hipStream_t stream) {
  (void)in_sizes; (void)n_in; (void)out_size; (void)ws_size;
  const float* q  = (const float*)d_in[0];
  const float* k  = (const float*)d_in[1];
  const float* v  = (const float*)d_in[2];
  const float* Wq = (const float*)d_in[3];
  const float* Wk = (const float*)d_in[4];
  const float* Wv = (const float*)d_in[5];
  const float* Wo = (const float*)d_in[6];

  unsigned short* Qh  = (unsigned short*)d_ws;
  unsigned short* Kh  = Qh + (size_t)2 * NH * S_LEN * DH;
  unsigned short* Vt  = Kh + (size_t)2 * KVH * S_LEN * DH;
  unsigned short* Z   = Vt + (size_t)2 * KVH * S_LEN * DH;
  unsigned short* vb  = Z + (size_t)4096 * 2048;
  unsigned short* Wqt = vb + (size_t)4096 * 2048;
  unsigned short* Wkt = Wqt + (size_t)2048 * 2048;
  unsigned short* Wvt = Wkt + (size_t)512 * 2048;
  unsigned short* Wot = Wvt + (size_t)512 * 2048;
  // qb/kb live in d_out (dead before out_kernel writes d_out)
  unsigned short* qb = (unsigned short*)d_out;
  unsigned short* kb = qb + (size_t)4096 * 2048;

  const float scale = 0.29730177875068026f;  // 128^(-1/4), folded into Wq/Wk

  static int s_attr_done = 0;
  if (!s_attr_done) {
    hipFuncSetAttribute(reinterpret_cast<const void*>(proj_kernel),
                        hipFuncAttributeMaxDynamicSharedMemorySize, 131072);
    hipFuncSetAttribute(reinterpret_cast<const void*>(out_kernel),
                        hipFuncAttributeMaxDynamicSharedMemorySize, 131072);
    hipFuncSetAttribute(reinterpret_cast<const void*>(attn_kernel),
                        hipFuncAttributeMaxDynamicSharedMemorySize, 81920);
    s_attr_done = 1;
  }

  pre_kernel<<<22528, 256, 0, stream>>>(q, k, v, Wq, Wk, Wv, Wo,
                                        qb, kb, vb, Wqt, Wkt, Wvt, Wot, scale);
  proj_kernel<<<192, 512, 131072, stream>>>(qb, kb, vb, Wqt, Wkt, Wvt, Qh, Kh, Vt);
  attn_kernel<<<dim3(16, 16, 2), 256, 81920, stream>>>(Qh, Kh, Vt, Z);
  out_kernel<<<128, 512, 131072, stream>>>(Z, Wot, (float*)d_out);
}

// Round 6
// 335.193 us; speedup vs baseline: 1.2427x; 1.0368x over previous
//
#include <hip/hip_runtime.h>

#define S_LEN 2048
#define EMB 2048
#define NH 16
#define KVH 4
#define DH 128

typedef __bf16 bf16x8 __attribute__((ext_vector_type(8)));
typedef float floatx4 __attribute__((ext_vector_type(4)));
typedef unsigned short ushortx8 __attribute__((ext_vector_type(8)));
typedef unsigned short ushortx4 __attribute__((ext_vector_type(4)));

static __device__ __forceinline__ unsigned short f2bf(float f) {
  unsigned u = __float_as_uint(f);
  return (unsigned short)((u + 0x7fffu + ((u >> 16) & 1u)) >> 16);
}

// async 16B global -> LDS (wave-uniform LDS base + lane*16)
static __device__ __forceinline__ void gload16(const unsigned short* g, unsigned short* l) {
  __builtin_amdgcn_global_load_lds(
      (const __attribute__((address_space(1))) unsigned int*)(const void*)g,
      (__attribute__((address_space(3))) unsigned int*)(void*)l, 16, 0, 0);
}

// ---- fused preprocessing: qkv fp32->bf16 (blocks 0..12287) + weight
// ---- transpose/scale/convert to [N][K] bf16 (blocks 12288..22527)
__global__ __launch_bounds__(256) void pre_kernel(
    const float* __restrict__ q, const float* __restrict__ k, const float* __restrict__ v,
    const float* __restrict__ Wq, const float* __restrict__ Wk,
    const float* __restrict__ Wv, const float* __restrict__ Wo,
    unsigned short* __restrict__ qo, unsigned short* __restrict__ ko,
    unsigned short* __restrict__ vo,
    unsigned short* __restrict__ Wqt, unsigned short* __restrict__ Wkt,
    unsigned short* __restrict__ Wvt, unsigned short* __restrict__ Wot,
    float scale) {
  __shared__ float t[32][33];
  int bx = blockIdx.x;
  if (bx < 12288) {
    const int sel = bx >> 12;
    const float* in = (sel == 0) ? q : (sel == 1) ? k : v;
    unsigned short* out = (sel == 0) ? qo : (sel == 1) ? ko : vo;
    size_t i = (((size_t)(bx & 4095)) * 256 + threadIdx.x) * 8;
    floatx4 a = *(const floatx4*)(in + i);
    floatx4 bvec = *(const floatx4*)(in + i + 4);
    ushortx8 o;
    #pragma unroll
    for (int c = 0; c < 4; ++c) { o[c] = f2bf(a[c]); o[4 + c] = f2bf(bvec[c]); }
    *(ushortx8*)(out + i) = o;
  } else {
    bx -= 12288;
    const float* W; unsigned short* Wt; int N, tile; float sc;
    if (bx < 4096)      { W = Wq; Wt = Wqt; N = 2048; tile = bx;        sc = scale; }
    else if (bx < 5120) { W = Wk; Wt = Wkt; N = 512;  tile = bx - 4096; sc = scale; }
    else if (bx < 6144) { W = Wv; Wt = Wvt; N = 512;  tile = bx - 5120; sc = 1.0f; }
    else                { W = Wo; Wt = Wot; N = 2048; tile = bx - 6144; sc = 1.0f; }
    const int ntiles = N >> 5;
    const int n0 = (tile % ntiles) * 32, k0 = (tile / ntiles) * 32;
    const int tx = threadIdx.x & 31, ty = threadIdx.x >> 5;
    #pragma unroll
    for (int r = 0; r < 4; ++r)
      t[ty + r * 8][tx] = W[(size_t)(k0 + ty + r * 8) * N + n0 + tx];
    __syncthreads();
    #pragma unroll
    for (int r = 0; r < 4; ++r)
      Wt[(size_t)(n0 + ty + r * 8) * 2048 + k0 + tx] = f2bf(t[tx][ty + r * 8] * sc);
  }
}

// ================= 256x256 / BK=64 / 8-wave / 8-phase GEMM core =================
// (unchanged from the 355.8us build; see schedule comment in R1/R2)
static __device__ __forceinline__ void gemm256_core(
    const unsigned short* __restrict__ Ab, const unsigned short* __restrict__ Bb,
    bool swap, unsigned short* As, unsigned short* Bs, floatx4 (&acc)[8][4]) {
  const int tid = threadIdx.x;
  const int lane = tid & 63, w = tid >> 6;
  const int lm = lane & 15, gq = lane >> 4;
  const int wm = w >> 2, wn = w & 3;
  const int lr = lane >> 3, lc = (lane & 7) ^ lr;

  auto stageH = [&](const unsigned short* gb, unsigned short* lt, int half, int kst) {
    #pragma unroll
    for (int qq = 0; qq < 2; ++qq) {
      const int rb = half * 128 + w * 16 + qq * 8;
      gload16(gb + (((size_t)(rb + lr)) << 11) + kst + (lc << 3), lt + rb * 64);
    }
  };

  unsigned short* As2 = As + 16384;
  unsigned short* Bs2 = Bs + 16384;

  // prologue: tile0 (all 4 halves) -> buf0; A(1)h0 -> buf1
  stageH(Ab, As, 0, 0);  stageH(Ab, As, 1, 0);
  stageH(Bb, Bs, 0, 0);  stageH(Bb, Bs, 1, 0);
  stageH(Ab, As2, 0, 64);
  asm volatile("s_waitcnt vmcnt(2)" ::: "memory");
  __builtin_amdgcn_s_barrier();

  const int r1 = (wm * 128 + lm) * 64;             // op1 row base (frag i: +i*1024)
  const int r2 = (wn * 64 + lm) * 64;              // op2 row base (frag j: +j*1024)
  const int c0 = ((0 + gq) ^ (lm & 7)) * 8;        // kk0 chunk (XOR-swizzled)
  const int c1 = ((4 + gq) ^ (lm & 7)) * 8;        // kk1 chunk

#define TILE_BODY(CA, CB, OA, OB, KS1, KS2, STG1, STG4)                                         \
  {                                                                                             \
    const unsigned short* l1 = swap ? (CB) : (CA);                                              \
    const unsigned short* l2 = swap ? (CA) : (CB);                                              \
    bf16x8 op1[8], o2a[4], o2b[4];                                                              \
    _Pragma("unroll") for (int i = 0; i < 8; ++i)                                               \
      op1[i] = *(const bf16x8*)&l1[r1 + i * 1024 + c0];                                         \
    _Pragma("unroll") for (int j = 0; j < 4; ++j)                                               \
      o2a[j] = *(const bf16x8*)&l2[r2 + j * 1024 + c0];                                         \
    if (STG1) stageH(Ab, (OA), 1, (KS1));                                                       \
    __builtin_amdgcn_s_barrier();                                                               \
    asm volatile("s_waitcnt lgkmcnt(0)" ::: "memory");                                          \
    __builtin_amdgcn_s_setprio(1);                                                              \
    _Pragma("unroll") for (int i = 0; i < 8; ++i) {                                             \
      acc[i][0] = __builtin_amdgcn_mfma_f32_16x16x32_bf16(op1[i], o2a[0], acc[i][0], 0, 0, 0);  \
      acc[i][1] = __builtin_amdgcn_mfma_f32_16x16x32_bf16(op1[i], o2a[1], acc[i][1], 0, 0, 0);  \
    }                                                                                           \
    __builtin_amdgcn_s_setprio(0);                                                              \
    __builtin_amdgcn_s_barrier();                                                               \
    _Pragma("unroll") for (int j = 0; j < 4; ++j)                                               \
      o2b[j] = *(const bf16x8*)&l2[r2 + j * 1024 + c1];                                         \
    if (STG1) stageH(Bb, (OB), 0, (KS1));                                                       \
    __builtin_amdgcn_s_barrier();                                                               \
    asm volatile("s_waitcnt lgkmcnt(0)" ::: "memory");                                          \
    __builtin_amdgcn_s_setprio(1);                                                              \
    _Pragma("unroll") for (int i = 0; i < 8; ++i) {                                             \
      acc[i][2] = __builtin_amdgcn_mfma_f32_16x16x32_bf16(op1[i], o2a[2], acc[i][2], 0, 0, 0);  \
      acc[i][3] = __builtin_amdgcn_mfma_f32_16x16x32_bf16(op1[i], o2a[3], acc[i][3], 0, 0, 0);  \
    }                                                                                           \
    __builtin_amdgcn_s_setprio(0);                                                               \
    __builtin_amdgcn_s_barrier();                                                               \
    _Pragma("unroll") for (int i = 0; i < 8; ++i)                                               \
      op1[i] = *(const bf16x8*)&l1[r1 + i * 1024 + c1];                                         \
    if (STG1) stageH(Bb, (OB), 1, (KS1));                                                       \
    __builtin_amdgcn_s_barrier();                                                               \
    asm volatile("s_waitcnt lgkmcnt(0)" ::: "memory");                                          \
    __builtin_amdgcn_s_setprio(1);                                                              \
    _Pragma("unroll") for (int i = 0; i < 8; ++i) {                                             \
      acc[i][0] = __builtin_amdgcn_mfma_f32_16x16x32_bf16(op1[i], o2b[0], acc[i][0], 0, 0, 0);  \
      acc[i][1] = __builtin_amdgcn_mfma_f32_16x16x32_bf16(op1[i], o2b[1], acc[i][1], 0, 0, 0);  \
    }                                                                                           \
    __builtin_amdgcn_s_setprio(0);                                                               \
    __builtin_amdgcn_s_barrier();                                                               \
    if (STG4) stageH(Ab, (CA), 0, (KS2));                                                       \
    __builtin_amdgcn_s_barrier();                                                               \
    __builtin_amdgcn_s_setprio(1);                                                              \
    _Pragma("unroll") for (int i = 0; i < 8; ++i) {                                             \
      acc[i][2] = __builtin_amdgcn_mfma_f32_16x16x32_bf16(op1[i], o2b[2], acc[i][2], 0, 0, 0);  \
      acc[i][3] = __builtin_amdgcn_mfma_f32_16x16x32_bf16(op1[i], o2b[3], acc[i][3], 0, 0, 0);  \
    }                                                                                           \
    __builtin_amdgcn_s_setprio(0);                                                               \
    if (STG4) { asm volatile("s_waitcnt vmcnt(2)" ::: "memory"); }                              \
    else      { asm volatile("s_waitcnt vmcnt(0)" ::: "memory"); }                              \
    __builtin_amdgcn_s_barrier();                                                               \
  }

  #pragma unroll 1
  for (int t = 0; t < 30; t += 2) {
    TILE_BODY(As, Bs, As2, Bs2, (t + 1) * 64, (t + 2) * 64, 1, 1);
    TILE_BODY(As2, Bs2, As, Bs, (t + 2) * 64, (t + 3) * 64, 1, 1);
  }
  TILE_BODY(As, Bs, As2, Bs2, 31 * 64, 0, 1, 0);
  TILE_BODY(As2, Bs2, As, Bs, 0, 0, 0, 0);
#undef TILE_BODY
}

// ---- merged Q/K/V projection GEMM: 192 blocks of 256x256, K=2048 ----
__global__ __launch_bounds__(512, 2) void proj_kernel(
    const unsigned short* __restrict__ qb, const unsigned short* __restrict__ kb,
    const unsigned short* __restrict__ vb,
    const unsigned short* __restrict__ Wqt, const unsigned short* __restrict__ Wkt,
    const unsigned short* __restrict__ Wvt,
    unsigned short* __restrict__ Qh, unsigned short* __restrict__ Kh,
    unsigned short* __restrict__ Vt) {
  extern __shared__ unsigned short lds[];
  unsigned short* As = lds;            // 2 x 16384
  unsigned short* Bs = lds + 32768;    // 2 x 16384
  int bid = (int)blockIdx.x;
  bid = (bid & 7) * 24 + (bid >> 3);   // XCD swizzle (192 % 8 == 0 -> bijective)
  const unsigned short *Ab, *Bb;
  int task, bn, bt;
  if (bid < 128)      { task = 0; bn = bid >> 4;         bt = bid & 15;         Ab = qb; Bb = Wqt; }
  else if (bid < 160) { task = 1; bn = (bid - 128) >> 4; bt = (bid - 128) & 15; Ab = kb; Bb = Wkt; }
  else                { task = 2; bn = (bid - 160) >> 4; bt = (bid - 160) & 15; Ab = vb; Bb = Wvt; }
  Ab += ((size_t)bt) << 19;   // bt*256*2048
  Bb += ((size_t)bn) << 19;

  floatx4 acc[8][4] = {};
  gemm256_core(Ab, Bb, task != 2, As, Bs, acc);

  const int tid = threadIdx.x, lane = tid & 63, w = tid >> 6;
  const int lm = lane & 15, gq = lane >> 4;
  const int wm = w >> 2, wn = w & 3;
  if (task != 2) {           // Q/K: rows=d (weight n-dim), cols=t
    unsigned short* outp = (task == 0) ? Qh : Kh;
    const int nheads = (task == 0) ? NH : KVH;
    const int head = bn * 2 + wm;
    #pragma unroll
    for (int i = 0; i < 8; ++i) {
      const int d0 = i * 16 + gq * 4;
      #pragma unroll
      for (int j = 0; j < 4; ++j) {
        const int tg = bt * 256 + wn * 64 + j * 16 + lm;
        const int b_ = tg >> 11, s_ = tg & 2047;
        ushortx4 pk;
        #pragma unroll
        for (int r = 0; r < 4; ++r) pk[r] = f2bf(acc[i][j][r]);
        *(ushortx4*)&outp[((size_t)(b_ * nheads + head) * S_LEN + s_) * DH + d0] = pk;
      }
    }
  } else {                   // V: rows=s, cols=d -> Vt [B,KVH,D,S]
    #pragma unroll
    for (int i = 0; i < 8; ++i) {
      const int sgl = bt * 256 + wm * 128 + i * 16 + gq * 4;
      const int b_ = sgl >> 11, s_ = sgl & 2047;
      #pragma unroll
      for (int j = 0; j < 4; ++j) {
        const int dl = wn * 64 + j * 16;
        const int head = bn * 2 + (dl >> 7);
        const int dd = (dl & 127) + lm;
        ushortx4 pk;
        #pragma unroll
        for (int r = 0; r < 4; ++r) pk[r] = f2bf(acc[i][j][r]);
        *(ushortx4*)&Vt[((size_t)(b_ * KVH + head) * DH + dd) * S_LEN + s_] = pk;
      }
    }
  }
}

// ---- final GEMM: out[t][n] fp32 = Z[t][k] * Wot[n][k]^T, 128 blocks 256x256 ----
__global__ __launch_bounds__(512, 2) void out_kernel(const unsigned short* __restrict__ Z,
                                                     const unsigned short* __restrict__ Wot,
                                                     float* __restrict__ outp) {
  extern __shared__ unsigned short lds[];
  unsigned short* As = lds;
  unsigned short* Bs = lds + 32768;
  int bid = (int)blockIdx.x;
  bid = (bid & 7) * 16 + (bid >> 3);   // XCD swizzle (128 % 8 == 0)
  const int bn = bid >> 4, bt = bid & 15;

  floatx4 acc[8][4] = {};
  gemm256_core(Z + (((size_t)bt) << 19), Wot + (((size_t)bn) << 19), true, As, Bs, acc);

  const int tid = threadIdx.x, lane = tid & 63, w = tid >> 6;
  const int lm = lane & 15, gq = lane >> 4;
  const int wm = w >> 2, wn = w & 3;
  #pragma unroll
  for (int i = 0; i < 8; ++i) {
    const int n0 = bn * 256 + wm * 128 + i * 16 + gq * 4;
    #pragma unroll
    for (int j = 0; j < 4; ++j) {
      const int tg = bt * 256 + wn * 64 + j * 16 + lm;
      *(floatx4*)&outp[(size_t)tg * 2048 + n0] = acc[i][j];
    }
  }
}

// ---- flash-style causal attention, 8-wave blocks with kv-split wave pairs:
// q-tile 128/block; per block-iter the block consumes kv-128: waves whi=w>>2
// handle kv-half whi (independent between barriers -> 2 waves/SIMD hide each
// other's latencies; deterministic balance: pass pairing gives 17 block-iters
// per block uniformly). K/V DMA-staged [128][128] double buffers with XOR
// chunk swizzle (zero ds_writes). Partial O/l accumulate in registers per
// parity; combined once per pass via the then-dead K/V LDS as scratch.
__global__ __launch_bounds__(512, 2) void attn_kernel(const unsigned short* __restrict__ Qh,
                                                      const unsigned short* __restrict__ Kh,
                                                      const unsigned short* __restrict__ Vt,
                                                      unsigned short* __restrict__ Z) {
  extern __shared__ unsigned short alds[];
  unsigned short* KsB = alds;            // 2 x [128][128] = 65536 B
  unsigned short* VsB = alds + 32768;    // 2 x [128 d][128 s] = 65536 B
  unsigned short* PsB = alds + 65536;    // 8 waves x [16][64] = 16384 B  (total 144 KB)
  const int tid = threadIdx.x;
  const int w = tid >> 6, lane = tid & 63;
  const int wlo = w & 3, whi = w >> 2;
  const int lm = lane & 15, gq = lane >> 4;
  const int h = blockIdx.y, b = blockIdx.z;
  const unsigned short* Kp = Kh + (size_t)(b * KVH + (h >> 2)) * S_LEN * DH;
  const unsigned short* Vp = Vt + (size_t)(b * KVH + (h >> 2)) * DH * S_LEN;
  unsigned short* psW = PsB + w * (16 * 64);

  // DMA maps ([128][128] tile, 16 chunks/row): instr i, wave w covers chunk
  // idx = i*512 + w*64 + lane -> row = i*32 + w*4 + (lane>>4), colchunk = lane&15;
  // source col chunk = colchunk ^ (row&7); (row&7) = (w*4 + (lane>>4)) & 7.
  const int dr = lane >> 4;
  const int srcswz = ((lane & 15) ^ ((w * 4 + dr) & 7)) * 8;
  auto loadK = [&](int kv, int bsel) {
    unsigned short* dst = KsB + bsel * 16384 + w * 512;
    #pragma unroll
    for (int i = 0; i < 4; ++i)
      gload16(Kp + (size_t)(kv + i * 32 + w * 4 + dr) * DH + srcswz, dst + i * 4096);
  };
  auto loadV = [&](int kv, int bsel) {
    unsigned short* dst = VsB + bsel * 16384 + w * 512;
    #pragma unroll
    for (int i = 0; i < 4; ++i)
      gload16(Vp + (size_t)(i * 32 + w * 4 + dr) * S_LEN + kv + srcswz, dst + i * 4096);
  };

  // read-side swizzled chunk offsets
  int kcol[4];
  #pragma unroll
  for (int kk = 0; kk < 4; ++kk) kcol[kk] = ((kk * 4 + gq) ^ (lm & 7)) * 8;
  const int sw0 = (whi * 8 + (gq ^ (lm & 7))) * 8;
  const int sw1 = (whi * 8 + ((4 | gq) ^ (lm & 7))) * 8;

  bf16x8 ones;
  #pragma unroll
  for (int c = 0; c < 8; ++c) ones[c] = (__bf16)1.0f;

  #pragma unroll 1
  for (int pass = 0; pass < 2; ++pass) {
    const int qt = pass ? (int)blockIdx.x : 15 - (int)blockIdx.x;
    const int Q0 = qt * 128;
    const int nit = qt + 1;
    const unsigned short* Qp = Qh + ((size_t)(b * NH + h) * S_LEN + Q0) * DH;
    bf16x8 qfr[2][4];
    #pragma unroll
    for (int g = 0; g < 2; ++g)
      #pragma unroll
      for (int kk = 0; kk < 4; ++kk)
        qfr[g][kk] = *(const bf16x8*)(Qp + (size_t)(wlo * 32 + g * 16 + lm) * DH + kk * 32 + gq * 8);

    floatx4 acc_o[2][8] = {};
    floatx4 acc_l[2] = {};

    loadK(0, 0);
    loadV(0, 0);
    asm volatile("s_waitcnt vmcnt(0)" ::: "memory");
    __builtin_amdgcn_s_barrier();
    int buf = 0;

    #pragma unroll 1
    for (int it = 0; it < nit; ++it) {
      const int kv0 = it * 128;
      const unsigned short* Kc = KsB + buf * 16384 + (whi * 64) * 128;  // wave's K half
      const unsigned short* Vc = VsB + buf * 16384;
      if (it + 1 < nit) { loadK(kv0 + 128, buf ^ 1); loadV(kv0 + 128, buf ^ 1); }
      // S = Q K^T over the wave's kv-half
      bf16x8 kreg[4][4];
      #pragma unroll
      for (int j = 0; j < 4; ++j)
        #pragma unroll
        for (int kk = 0; kk < 4; ++kk)
          kreg[j][kk] = *(const bf16x8*)&Kc[(j * 16 + lm) * 128 + kcol[kk]];
      floatx4 sa[2][4] = {};
      #pragma unroll
      for (int g = 0; g < 2; ++g)
        #pragma unroll
        for (int j = 0; j < 4; ++j)
          #pragma unroll
          for (int kk = 0; kk < 4; ++kk)
            sa[g][j] = __builtin_amdgcn_mfma_f32_16x16x32_bf16(qfr[g][kk], kreg[j][kk], sa[g][j], 0, 0, 0);
      // masked exp -> Ps ([16][64]/wave, reused g=0 then g=1; same-wave order)
      bf16x8 ap[2][2];
      #pragma unroll
      for (int g = 0; g < 2; ++g) {
        const int rowb = Q0 + wlo * 32 + g * 16 + gq * 4;
        #pragma unroll
        for (int r = 0; r < 4; ++r) {
          const int qg = rowb + r;
          const int prow = gq * 4 + r;
          #pragma unroll
          for (int j = 0; j < 4; ++j) {
            const int kg = kv0 + whi * 64 + j * 16 + lm;
            const float p = (kg <= qg) ? __expf(sa[g][j][r]) : 0.0f;
            const int pcol = j * 16 + lm;
            psW[prow * 64 + (((pcol >> 3) ^ (prow & 7)) << 3) + (pcol & 7)] =
                __builtin_bit_cast(unsigned short, (__bf16)p);
          }
        }
        ap[g][0] = *(const bf16x8*)&psW[lm * 64 + ((gq ^ (lm & 7)) << 3)];
        ap[g][1] = *(const bf16x8*)&psW[lm * 64 + (((4 | gq) ^ (lm & 7)) << 3)];
      }
      // P V swapped over the wave's s-half; V reads shared by both row-groups
      #pragma unroll
      for (int jd = 0; jd < 8; ++jd) {
        const int row = (jd * 16 + lm) * 128;
        bf16x8 bv0 = *(const bf16x8*)&Vc[row + sw0];
        bf16x8 bv1 = *(const bf16x8*)&Vc[row + sw1];
        #pragma unroll
        for (int g = 0; g < 2; ++g) {
          acc_o[g][jd] = __builtin_amdgcn_mfma_f32_16x16x32_bf16(bv0, ap[g][0], acc_o[g][jd], 0, 0, 0);
          acc_o[g][jd] = __builtin_amdgcn_mfma_f32_16x16x32_bf16(bv1, ap[g][1], acc_o[g][jd], 0, 0, 0);
        }
      }
      #pragma unroll
      for (int g = 0; g < 2; ++g) {
        acc_l[g] = __builtin_amdgcn_mfma_f32_16x16x32_bf16(ones, ap[g][0], acc_l[g], 0, 0, 0);
        acc_l[g] = __builtin_amdgcn_mfma_f32_16x16x32_bf16(ones, ap[g][1], acc_l[g], 0, 0, 0);
      }
      asm volatile("s_waitcnt vmcnt(0) lgkmcnt(0)" ::: "memory");
      __builtin_amdgcn_s_barrier();
      buf ^= 1;
    }

    // combine parity partial sums via dead K/V LDS, whi==0 stores Z
    float* scO = (float*)KsB;   // 16384 floats: wave wlo at + wlo*4096
    float* scL = (float*)VsB;   // wave wlo at + wlo*128
    if (whi == 1) {
      #pragma unroll
      for (int g = 0; g < 2; ++g) {
        #pragma unroll
        for (int jd = 0; jd < 8; ++jd)
          #pragma unroll
          for (int r = 0; r < 4; ++r)
            scO[wlo * 4096 + (g * 32 + jd * 4 + r) * 64 + lane] = acc_o[g][jd][r];
        scL[wlo * 128 + g * 64 + lane] = acc_l[g][0];
      }
    }
    __syncthreads();
    if (whi == 0) {
      #pragma unroll
      for (int g = 0; g < 2; ++g) {
        const float inv = 1.0f / (acc_l[g][0] + scL[wlo * 128 + g * 64 + lane]);
        const size_t t_ = (size_t)b * S_LEN + Q0 + wlo * 32 + g * 16 + lm;
        #pragma unroll
        for (int jd = 0; jd < 8; ++jd) {
          ushortx4 pk;
          #pragma unroll
          for (int r = 0; r < 4; ++r)
            pk[r] = f2bf((acc_o[g][jd][r] + scO[wlo * 4096 + (g * 32 + jd * 4 + r) * 64 + lane]) * inv);
          *(ushortx4*)&Z[t_ * (NH * DH) + h * DH + jd * 16 + gq * 4] = pk;
        }
      }
    }
    __syncthreads();  // scratch/buffers dead before next pass's staging
  }
}

extern "C" void kernel_launch(void* const* d_in, const int* in_sizes, int n_in,
                              void* d_out, int out_size, void* d_ws, size_t ws_size,
                              hipStream_t stream) {
  (void)in_sizes; (void)n_in; (void)out_size; (void)ws_size;
  const float* q  = (const float*)d_in[0];
  const float* k  = (const float*)d_in[1];
  const float* v  = (const float*)d_in[2];
  const float* Wq = (const float*)d_in[3];
  const float* Wk = (const float*)d_in[4];
  const float* Wv = (const float*)d_in[5];
  const float* Wo = (const float*)d_in[6];

  unsigned short* Qh  = (unsigned short*)d_ws;
  unsigned short* Kh  = Qh + (size_t)2 * NH * S_LEN * DH;
  unsigned short* Vt  = Kh + (size_t)2 * KVH * S_LEN * DH;
  unsigned short* Z   = Vt + (size_t)2 * KVH * S_LEN * DH;
  unsigned short* vb  = Z + (size_t)4096 * 2048;
  unsigned short* Wqt = vb + (size_t)4096 * 2048;
  unsigned short* Wkt = Wqt + (size_t)2048 * 2048;
  unsigned short* Wvt = Wkt + (size_t)512 * 2048;
  unsigned short* Wot = Wvt + (size_t)512 * 2048;
  // qb/kb live in d_out (dead before out_kernel writes d_out)
  unsigned short* qb = (unsigned short*)d_out;
  unsigned short* kb = qb + (size_t)4096 * 2048;

  const float scale = 0.29730177875068026f;  // 128^(-1/4), folded into Wq/Wk

  static int s_attr_done = 0;
  if (!s_attr_done) {
    hipFuncSetAttribute(reinterpret_cast<const void*>(proj_kernel),
                        hipFuncAttributeMaxDynamicSharedMemorySize, 131072);
    hipFuncSetAttribute(reinterpret_cast<const void*>(out_kernel),
                        hipFuncAttributeMaxDynamicSharedMemorySize, 131072);
    hipFuncSetAttribute(reinterpret_cast<const void*>(attn_kernel),
                        hipFuncAttributeMaxDynamicSharedMemorySize, 147456);
    s_attr_done = 1;
  }

  pre_kernel<<<22528, 256, 0, stream>>>(q, k, v, Wq, Wk, Wv, Wo,
                                        qb, kb, vb, Wqt, Wkt, Wvt, Wot, scale);
  proj_kernel<<<192, 512, 131072, stream>>>(qb, kb, vb, Wqt, Wkt, Wvt, Qh, Kh, Vt);
  attn_kernel<<<dim3(8, 16, 2), 512, 147456, stream>>>(Qh, Kh, Vt, Z);
  out_kernel<<<128, 512, 131072, stream>>>(Z, Wot, (float*)d_out);
}

// Round 7
// 325.758 us; speedup vs baseline: 1.2787x; 1.0290x over previous
//
#include <hip/hip_runtime.h>

#define S_LEN 2048
#define EMB 2048
#define NH 16
#define KVH 4
#define DH 128

typedef __bf16 bf16x8 __attribute__((ext_vector_type(8)));
typedef float floatx4 __attribute__((ext_vector_type(4)));
typedef unsigned short ushortx8 __attribute__((ext_vector_type(8)));
typedef unsigned short ushortx4 __attribute__((ext_vector_type(4)));

static __device__ __forceinline__ unsigned short f2bf(float f) {
  unsigned u = __float_as_uint(f);
  return (unsigned short)((u + 0x7fffu + ((u >> 16) & 1u)) >> 16);
}

// async 16B global -> LDS (wave-uniform LDS base + lane*16)
static __device__ __forceinline__ void gload16(const unsigned short* g, unsigned short* l) {
  __builtin_amdgcn_global_load_lds(
      (const __attribute__((address_space(1))) unsigned int*)(const void*)g,
      (__attribute__((address_space(3))) unsigned int*)(void*)l, 16, 0, 0);
}

// ---- fused preprocessing: qkv fp32->bf16 (blocks 0..12287) + weight
// ---- transpose/scale/convert to [N][K] bf16 (blocks 12288..22527)
__global__ __launch_bounds__(256) void pre_kernel(
    const float* __restrict__ q, const float* __restrict__ k, const float* __restrict__ v,
    const float* __restrict__ Wq, const float* __restrict__ Wk,
    const float* __restrict__ Wv, const float* __restrict__ Wo,
    unsigned short* __restrict__ qo, unsigned short* __restrict__ ko,
    unsigned short* __restrict__ vo,
    unsigned short* __restrict__ Wqt, unsigned short* __restrict__ Wkt,
    unsigned short* __restrict__ Wvt, unsigned short* __restrict__ Wot,
    float scale) {
  __shared__ float t[32][33];
  int bx = blockIdx.x;
  if (bx < 12288) {
    const int sel = bx >> 12;
    const float* in = (sel == 0) ? q : (sel == 1) ? k : v;
    unsigned short* out = (sel == 0) ? qo : (sel == 1) ? ko : vo;
    size_t i = (((size_t)(bx & 4095)) * 256 + threadIdx.x) * 8;
    floatx4 a = *(const floatx4*)(in + i);
    floatx4 bvec = *(const floatx4*)(in + i + 4);
    ushortx8 o;
    #pragma unroll
    for (int c = 0; c < 4; ++c) { o[c] = f2bf(a[c]); o[4 + c] = f2bf(bvec[c]); }
    *(ushortx8*)(out + i) = o;
  } else {
    bx -= 12288;
    const float* W; unsigned short* Wt; int N, tile; float sc;
    if (bx < 4096)      { W = Wq; Wt = Wqt; N = 2048; tile = bx;        sc = scale; }
    else if (bx < 5120) { W = Wk; Wt = Wkt; N = 512;  tile = bx - 4096; sc = scale; }
    else if (bx < 6144) { W = Wv; Wt = Wvt; N = 512;  tile = bx - 5120; sc = 1.0f; }
    else                { W = Wo; Wt = Wot; N = 2048; tile = bx - 6144; sc = 1.0f; }
    const int ntiles = N >> 5;
    const int n0 = (tile % ntiles) * 32, k0 = (tile / ntiles) * 32;
    const int tx = threadIdx.x & 31, ty = threadIdx.x >> 5;
    #pragma unroll
    for (int r = 0; r < 4; ++r)
      t[ty + r * 8][tx] = W[(size_t)(k0 + ty + r * 8) * N + n0 + tx];
    __syncthreads();
    #pragma unroll
    for (int r = 0; r < 4; ++r)
      Wt[(size_t)(n0 + ty + r * 8) * 2048 + k0 + tx] = f2bf(t[tx][ty + r * 8] * sc);
  }
}

// ================= 256x256 / BK=64 / 8-wave / 8-phase GEMM core =================
// (unchanged from the 355.8us build; see schedule comment in R1/R2)
static __device__ __forceinline__ void gemm256_core(
    const unsigned short* __restrict__ Ab, const unsigned short* __restrict__ Bb,
    bool swap, unsigned short* As, unsigned short* Bs, floatx4 (&acc)[8][4]) {
  const int tid = threadIdx.x;
  const int lane = tid & 63, w = tid >> 6;
  const int lm = lane & 15, gq = lane >> 4;
  const int wm = w >> 2, wn = w & 3;
  const int lr = lane >> 3, lc = (lane & 7) ^ lr;

  auto stageH = [&](const unsigned short* gb, unsigned short* lt, int half, int kst) {
    #pragma unroll
    for (int qq = 0; qq < 2; ++qq) {
      const int rb = half * 128 + w * 16 + qq * 8;
      gload16(gb + (((size_t)(rb + lr)) << 11) + kst + (lc << 3), lt + rb * 64);
    }
  };

  unsigned short* As2 = As + 16384;
  unsigned short* Bs2 = Bs + 16384;

  // prologue: tile0 (all 4 halves) -> buf0; A(1)h0 -> buf1
  stageH(Ab, As, 0, 0);  stageH(Ab, As, 1, 0);
  stageH(Bb, Bs, 0, 0);  stageH(Bb, Bs, 1, 0);
  stageH(Ab, As2, 0, 64);
  asm volatile("s_waitcnt vmcnt(2)" ::: "memory");
  __builtin_amdgcn_s_barrier();

  const int r1 = (wm * 128 + lm) * 64;             // op1 row base (frag i: +i*1024)
  const int r2 = (wn * 64 + lm) * 64;              // op2 row base (frag j: +j*1024)
  const int c0 = ((0 + gq) ^ (lm & 7)) * 8;        // kk0 chunk (XOR-swizzled)
  const int c1 = ((4 + gq) ^ (lm & 7)) * 8;        // kk1 chunk

#define TILE_BODY(CA, CB, OA, OB, KS1, KS2, STG1, STG4)                                         \
  {                                                                                             \
    const unsigned short* l1 = swap ? (CB) : (CA);                                              \
    const unsigned short* l2 = swap ? (CA) : (CB);                                              \
    bf16x8 op1[8], o2a[4], o2b[4];                                                              \
    _Pragma("unroll") for (int i = 0; i < 8; ++i)                                               \
      op1[i] = *(const bf16x8*)&l1[r1 + i * 1024 + c0];                                         \
    _Pragma("unroll") for (int j = 0; j < 4; ++j)                                               \
      o2a[j] = *(const bf16x8*)&l2[r2 + j * 1024 + c0];                                         \
    if (STG1) stageH(Ab, (OA), 1, (KS1));                                                       \
    __builtin_amdgcn_s_barrier();                                                               \
    asm volatile("s_waitcnt lgkmcnt(0)" ::: "memory");                                          \
    __builtin_amdgcn_s_setprio(1);                                                              \
    _Pragma("unroll") for (int i = 0; i < 8; ++i) {                                             \
      acc[i][0] = __builtin_amdgcn_mfma_f32_16x16x32_bf16(op1[i], o2a[0], acc[i][0], 0, 0, 0);  \
      acc[i][1] = __builtin_amdgcn_mfma_f32_16x16x32_bf16(op1[i], o2a[1], acc[i][1], 0, 0, 0);  \
    }                                                                                           \
    __builtin_amdgcn_s_setprio(0);                                                              \
    __builtin_amdgcn_s_barrier();                                                               \
    _Pragma("unroll") for (int j = 0; j < 4; ++j)                                               \
      o2b[j] = *(const bf16x8*)&l2[r2 + j * 1024 + c1];                                         \
    if (STG1) stageH(Bb, (OB), 0, (KS1));                                                       \
    __builtin_amdgcn_s_barrier();                                                               \
    asm volatile("s_waitcnt lgkmcnt(0)" ::: "memory");                                          \
    __builtin_amdgcn_s_setprio(1);                                                              \
    _Pragma("unroll") for (int i = 0; i < 8; ++i) {                                             \
      acc[i][2] = __builtin_amdgcn_mfma_f32_16x16x32_bf16(op1[i], o2a[2], acc[i][2], 0, 0, 0);  \
      acc[i][3] = __builtin_amdgcn_mfma_f32_16x16x32_bf16(op1[i], o2a[3], acc[i][3], 0, 0, 0);  \
    }                                                                                           \
    __builtin_amdgcn_s_setprio(0);                                                               \
    __builtin_amdgcn_s_barrier();                                                               \
    _Pragma("unroll") for (int i = 0; i < 8; ++i)                                               \
      op1[i] = *(const bf16x8*)&l1[r1 + i * 1024 + c1];                                         \
    if (STG1) stageH(Bb, (OB), 1, (KS1));                                                       \
    __builtin_amdgcn_s_barrier();                                                               \
    asm volatile("s_waitcnt lgkmcnt(0)" ::: "memory");                                          \
    __builtin_amdgcn_s_setprio(1);                                                              \
    _Pragma("unroll") for (int i = 0; i < 8; ++i) {                                             \
      acc[i][0] = __builtin_amdgcn_mfma_f32_16x16x32_bf16(op1[i], o2b[0], acc[i][0], 0, 0, 0);  \
      acc[i][1] = __builtin_amdgcn_mfma_f32_16x16x32_bf16(op1[i], o2b[1], acc[i][1], 0, 0, 0);  \
    }                                                                                           \
    __builtin_amdgcn_s_setprio(0);                                                               \
    __builtin_amdgcn_s_barrier();                                                               \
    if (STG4) stageH(Ab, (CA), 0, (KS2));                                                       \
    __builtin_amdgcn_s_barrier();                                                               \
    __builtin_amdgcn_s_setprio(1);                                                              \
    _Pragma("unroll") for (int i = 0; i < 8; ++i) {                                             \
      acc[i][2] = __builtin_amdgcn_mfma_f32_16x16x32_bf16(op1[i], o2b[2], acc[i][2], 0, 0, 0);  \
      acc[i][3] = __builtin_amdgcn_mfma_f32_16x16x32_bf16(op1[i], o2b[3], acc[i][3], 0, 0, 0);  \
    }                                                                                           \
    __builtin_amdgcn_s_setprio(0);                                                               \
    if (STG4) { asm volatile("s_waitcnt vmcnt(2)" ::: "memory"); }                              \
    else      { asm volatile("s_waitcnt vmcnt(0)" ::: "memory"); }                              \
    __builtin_amdgcn_s_barrier();                                                               \
  }

  #pragma unroll 1
  for (int t = 0; t < 30; t += 2) {
    TILE_BODY(As, Bs, As2, Bs2, (t + 1) * 64, (t + 2) * 64, 1, 1);
    TILE_BODY(As2, Bs2, As, Bs, (t + 2) * 64, (t + 3) * 64, 1, 1);
  }
  TILE_BODY(As, Bs, As2, Bs2, 31 * 64, 0, 1, 0);
  TILE_BODY(As2, Bs2, As, Bs, 0, 0, 0, 0);
#undef TILE_BODY
}

// ========== 256(big,op2) x 128(small,op1) / BK=64 core (for out_kernel) ==========
// Same spread-staging schedule; 6 loads/tile: P1 big(t+1)h1 -> other, P2 small(t+1)
// -> other, P4 big(t+2)h0 -> current, vmcnt(2) once per tile (carried big(t+1)h0
// from prev body + 4 this body drain; big(t+2)h0 stays in flight).
static __device__ __forceinline__ void gemm_bs_core(
    const unsigned short* __restrict__ Bigb, const unsigned short* __restrict__ Smb,
    unsigned short* As, unsigned short* Bs, floatx4 (&acc)[4][4]) {
  const int tid = threadIdx.x;
  const int lane = tid & 63, w = tid >> 6;
  const int lm = lane & 15, gq = lane >> 4;
  const int wm = w >> 2, wn = w & 3;
  const int lr = lane >> 3, lc = (lane & 7) ^ lr;

  auto stageH = [&](const unsigned short* gb, unsigned short* lt, int half, int kst) {
    #pragma unroll
    for (int qq = 0; qq < 2; ++qq) {
      const int rb = half * 128 + w * 16 + qq * 8;
      gload16(gb + (((size_t)(rb + lr)) << 11) + kst + (lc << 3), lt + rb * 64);
    }
  };

  unsigned short* As2 = As + 16384;  // big: 256x64 shorts per buf
  unsigned short* Bs2 = Bs + 8192;   // small: 128x64 shorts per buf

  // prologue: tile0 -> buf0; big(1)h0 -> buf1
  stageH(Bigb, As, 0, 0);  stageH(Bigb, As, 1, 0);
  stageH(Smb, Bs, 0, 0);
  stageH(Bigb, As2, 0, 64);
  asm volatile("s_waitcnt vmcnt(2)" ::: "memory");
  __builtin_amdgcn_s_barrier();

  const int r1 = (wm * 64 + lm) * 64;   // op1 (small) row base; frag i: +i*1024
  const int r2 = (wn * 64 + lm) * 64;   // op2 (big) row base; frag j: +j*1024
  const int c0 = ((0 + gq) ^ (lm & 7)) * 8;
  const int c1 = ((4 + gq) ^ (lm & 7)) * 8;

#define TB(CA, CB, OA, OB, KS1, KS2, STG1, STG4)                                                \
  {                                                                                             \
    bf16x8 op1[4], o2a[4], o2b[4];                                                              \
    _Pragma("unroll") for (int i = 0; i < 4; ++i)                                               \
      op1[i] = *(const bf16x8*)&(CB)[r1 + i * 1024 + c0];                                       \
    _Pragma("unroll") for (int j = 0; j < 4; ++j)                                               \
      o2a[j] = *(const bf16x8*)&(CA)[r2 + j * 1024 + c0];                                       \
    if (STG1) stageH(Bigb, (OA), 1, (KS1));                                                     \
    __builtin_amdgcn_s_barrier();                                                               \
    asm volatile("s_waitcnt lgkmcnt(0)" ::: "memory");                                          \
    __builtin_amdgcn_s_setprio(1);                                                              \
    _Pragma("unroll") for (int i = 0; i < 4; ++i) {                                             \
      acc[i][0] = __builtin_amdgcn_mfma_f32_16x16x32_bf16(op1[i], o2a[0], acc[i][0], 0, 0, 0);  \
      acc[i][1] = __builtin_amdgcn_mfma_f32_16x16x32_bf16(op1[i], o2a[1], acc[i][1], 0, 0, 0);  \
    }                                                                                           \
    __builtin_amdgcn_s_setprio(0);                                                              \
    __builtin_amdgcn_s_barrier();                                                               \
    _Pragma("unroll") for (int j = 0; j < 4; ++j)                                               \
      o2b[j] = *(const bf16x8*)&(CA)[r2 + j * 1024 + c1];                                       \
    if (STG1) stageH(Smb, (OB), 0, (KS1));                                                      \
    __builtin_amdgcn_s_barrier();                                                               \
    asm volatile("s_waitcnt lgkmcnt(0)" ::: "memory");                                          \
    __builtin_amdgcn_s_setprio(1);                                                              \
    _Pragma("unroll") for (int i = 0; i < 4; ++i) {                                             \
      acc[i][2] = __builtin_amdgcn_mfma_f32_16x16x32_bf16(op1[i], o2a[2], acc[i][2], 0, 0, 0);  \
      acc[i][3] = __builtin_amdgcn_mfma_f32_16x16x32_bf16(op1[i], o2a[3], acc[i][3], 0, 0, 0);  \
    }                                                                                           \
    __builtin_amdgcn_s_setprio(0);                                                              \
    __builtin_amdgcn_s_barrier();                                                               \
    _Pragma("unroll") for (int i = 0; i < 4; ++i)                                               \
      op1[i] = *(const bf16x8*)&(CB)[r1 + i * 1024 + c1];                                       \
    __builtin_amdgcn_s_barrier();                                                               \
    asm volatile("s_waitcnt lgkmcnt(0)" ::: "memory");                                          \
    __builtin_amdgcn_s_setprio(1);                                                              \
    _Pragma("unroll") for (int i = 0; i < 4; ++i) {                                             \
      acc[i][0] = __builtin_amdgcn_mfma_f32_16x16x32_bf16(op1[i], o2b[0], acc[i][0], 0, 0, 0);  \
      acc[i][1] = __builtin_amdgcn_mfma_f32_16x16x32_bf16(op1[i], o2b[1], acc[i][1], 0, 0, 0);  \
    }                                                                                           \
    __builtin_amdgcn_s_setprio(0);                                                              \
    __builtin_amdgcn_s_barrier();                                                               \
    if (STG4) stageH(Bigb, (CA), 0, (KS2));                                                     \
    __builtin_amdgcn_s_barrier();                                                               \
    __builtin_amdgcn_s_setprio(1);                                                              \
    _Pragma("unroll") for (int i = 0; i < 4; ++i) {                                             \
      acc[i][2] = __builtin_amdgcn_mfma_f32_16x16x32_bf16(op1[i], o2b[2], acc[i][2], 0, 0, 0);  \
      acc[i][3] = __builtin_amdgcn_mfma_f32_16x16x32_bf16(op1[i], o2b[3], acc[i][3], 0, 0, 0);  \
    }                                                                                           \
    __builtin_amdgcn_s_setprio(0);                                                              \
    if (STG4) { asm volatile("s_waitcnt vmcnt(2)" ::: "memory"); }                              \
    else      { asm volatile("s_waitcnt vmcnt(0)" ::: "memory"); }                              \
    __builtin_amdgcn_s_barrier();                                                               \
  }

  #pragma unroll 1
  for (int t = 0; t < 30; t += 2) {
    TB(As, Bs, As2, Bs2, (t + 1) * 64, (t + 2) * 64, 1, 1);
    TB(As2, Bs2, As, Bs, (t + 2) * 64, (t + 3) * 64, 1, 1);
  }
  TB(As, Bs, As2, Bs2, 31 * 64, 0, 1, 0);
  TB(As2, Bs2, As, Bs, 0, 0, 0, 0);
#undef TB
}

// ---- merged Q/K/V projection GEMM: 192 blocks of 256x256, K=2048 ----
__global__ __launch_bounds__(512, 2) void proj_kernel(
    const unsigned short* __restrict__ qb, const unsigned short* __restrict__ kb,
    const unsigned short* __restrict__ vb,
    const unsigned short* __restrict__ Wqt, const unsigned short* __restrict__ Wkt,
    const unsigned short* __restrict__ Wvt,
    unsigned short* __restrict__ Qh, unsigned short* __restrict__ Kh,
    unsigned short* __restrict__ Vt) {
  extern __shared__ unsigned short lds[];
  unsigned short* As = lds;            // 2 x 16384
  unsigned short* Bs = lds + 32768;    // 2 x 16384
  int bid = (int)blockIdx.x;
  bid = (bid & 7) * 24 + (bid >> 3);   // XCD swizzle (192 % 8 == 0 -> bijective)
  const unsigned short *Ab, *Bb;
  int task, bn, bt;
  if (bid < 128)      { task = 0; bn = bid >> 4;         bt = bid & 15;         Ab = qb; Bb = Wqt; }
  else if (bid < 160) { task = 1; bn = (bid - 128) >> 4; bt = (bid - 128) & 15; Ab = kb; Bb = Wkt; }
  else                { task = 2; bn = (bid - 160) >> 4; bt = (bid - 160) & 15; Ab = vb; Bb = Wvt; }
  Ab += ((size_t)bt) << 19;   // bt*256*2048
  Bb += ((size_t)bn) << 19;

  floatx4 acc[8][4] = {};
  gemm256_core(Ab, Bb, task != 2, As, Bs, acc);

  const int tid = threadIdx.x, lane = tid & 63, w = tid >> 6;
  const int lm = lane & 15, gq = lane >> 4;
  const int wm = w >> 2, wn = w & 3;
  if (task != 2) {           // Q/K: rows=d (weight n-dim), cols=t
    unsigned short* outp = (task == 0) ? Qh : Kh;
    const int nheads = (task == 0) ? NH : KVH;
    const int head = bn * 2 + wm;
    #pragma unroll
    for (int i = 0; i < 8; ++i) {
      const int d0 = i * 16 + gq * 4;
      #pragma unroll
      for (int j = 0; j < 4; ++j) {
        const int tg = bt * 256 + wn * 64 + j * 16 + lm;
        const int b_ = tg >> 11, s_ = tg & 2047;
        ushortx4 pk;
        #pragma unroll
        for (int r = 0; r < 4; ++r) pk[r] = f2bf(acc[i][j][r]);
        *(ushortx4*)&outp[((size_t)(b_ * nheads + head) * S_LEN + s_) * DH + d0] = pk;
      }
    }
  } else {                   // V: rows=s, cols=d -> Vt [B,KVH,D,S]
    #pragma unroll
    for (int i = 0; i < 8; ++i) {
      const int sgl = bt * 256 + wm * 128 + i * 16 + gq * 4;
      const int b_ = sgl >> 11, s_ = sgl & 2047;
      #pragma unroll
      for (int j = 0; j < 4; ++j) {
        const int dl = wn * 64 + j * 16;
        const int head = bn * 2 + (dl >> 7);
        const int dd = (dl & 127) + lm;
        ushortx4 pk;
        #pragma unroll
        for (int r = 0; r < 4; ++r) pk[r] = f2bf(acc[i][j][r]);
        *(ushortx4*)&Vt[((size_t)(b_ * KVH + head) * DH + dd) * S_LEN + s_] = pk;
      }
    }
  }
}

// ---- final GEMM: out[t][n] fp32 = Z[t][k] * Wot[n][k]^T ----
// 256 blocks of 256t x 128n (100% CU fill; was 128 blocks of 256x256 = 50%).
__global__ __launch_bounds__(512, 1) void out_kernel(const unsigned short* __restrict__ Z,
                                                     const unsigned short* __restrict__ Wot,
                                                     float* __restrict__ outp) {
  extern __shared__ unsigned short lds[];
  unsigned short* As = lds;          // big: Z tile 2 x (256x64) = 65536 B
  unsigned short* Bs = lds + 32768;  // small: Wot tile 2 x (128x64) = 32768 B
  int bid = (int)blockIdx.x;
  bid = (bid & 7) * 32 + (bid >> 3);   // XCD swizzle (256 % 8 == 0)
  const int bn = bid >> 4, bt = bid & 15;

  floatx4 acc[4][4] = {};
  gemm_bs_core(Z + (((size_t)bt) << 19), Wot + (((size_t)bn) << 18), As, Bs, acc);

  const int tid = threadIdx.x, lane = tid & 63, w = tid >> 6;
  const int lm = lane & 15, gq = lane >> 4;
  const int wm = w >> 2, wn = w & 3;
  #pragma unroll
  for (int i = 0; i < 4; ++i) {
    const int n0 = bn * 128 + wm * 64 + i * 16 + gq * 4;
    #pragma unroll
    for (int j = 0; j < 4; ++j) {
      const int tg = bt * 256 + wn * 64 + j * 16 + lm;
      *(floatx4*)&outp[(size_t)tg * 2048 + n0] = acc[i][j];
    }
  }
}

// ---- flash-style causal attention, 8-wave blocks with kv-split wave pairs
// (unchanged from the 335us build).
__global__ __launch_bounds__(512, 2) void attn_kernel(const unsigned short* __restrict__ Qh,
                                                      const unsigned short* __restrict__ Kh,
                                                      const unsigned short* __restrict__ Vt,
                                                      unsigned short* __restrict__ Z) {
  extern __shared__ unsigned short alds[];
  unsigned short* KsB = alds;            // 2 x [128][128] = 65536 B
  unsigned short* VsB = alds + 32768;    // 2 x [128 d][128 s] = 65536 B
  unsigned short* PsB = alds + 65536;    // 8 waves x [16][64] = 16384 B  (total 144 KB)
  const int tid = threadIdx.x;
  const int w = tid >> 6, lane = tid & 63;
  const int wlo = w & 3, whi = w >> 2;
  const int lm = lane & 15, gq = lane >> 4;
  const int h = blockIdx.y, b = blockIdx.z;
  const unsigned short* Kp = Kh + (size_t)(b * KVH + (h >> 2)) * S_LEN * DH;
  const unsigned short* Vp = Vt + (size_t)(b * KVH + (h >> 2)) * DH * S_LEN;
  unsigned short* psW = PsB + w * (16 * 64);

  const int dr = lane >> 4;
  const int srcswz = ((lane & 15) ^ ((w * 4 + dr) & 7)) * 8;
  auto loadK = [&](int kv, int bsel) {
    unsigned short* dst = KsB + bsel * 16384 + w * 512;
    #pragma unroll
    for (int i = 0; i < 4; ++i)
      gload16(Kp + (size_t)(kv + i * 32 + w * 4 + dr) * DH + srcswz, dst + i * 4096);
  };
  auto loadV = [&](int kv, int bsel) {
    unsigned short* dst = VsB + bsel * 16384 + w * 512;
    #pragma unroll
    for (int i = 0; i < 4; ++i)
      gload16(Vp + (size_t)(i * 32 + w * 4 + dr) * S_LEN + kv + srcswz, dst + i * 4096);
  };

  int kcol[4];
  #pragma unroll
  for (int kk = 0; kk < 4; ++kk) kcol[kk] = ((kk * 4 + gq) ^ (lm & 7)) * 8;
  const int sw0 = (whi * 8 + (gq ^ (lm & 7))) * 8;
  const int sw1 = (whi * 8 + ((4 | gq) ^ (lm & 7))) * 8;

  bf16x8 ones;
  #pragma unroll
  for (int c = 0; c < 8; ++c) ones[c] = (__bf16)1.0f;

  #pragma unroll 1
  for (int pass = 0; pass < 2; ++pass) {
    const int qt = pass ? (int)blockIdx.x : 15 - (int)blockIdx.x;
    const int Q0 = qt * 128;
    const int nit = qt + 1;
    const unsigned short* Qp = Qh + ((size_t)(b * NH + h) * S_LEN + Q0) * DH;
    bf16x8 qfr[2][4];
    #pragma unroll
    for (int g = 0; g < 2; ++g)
      #pragma unroll
      for (int kk = 0; kk < 4; ++kk)
        qfr[g][kk] = *(const bf16x8*)(Qp + (size_t)(wlo * 32 + g * 16 + lm) * DH + kk * 32 + gq * 8);

    floatx4 acc_o[2][8] = {};
    floatx4 acc_l[2] = {};

    loadK(0, 0);
    loadV(0, 0);
    asm volatile("s_waitcnt vmcnt(0)" ::: "memory");
    __builtin_amdgcn_s_barrier();
    int buf = 0;

    #pragma unroll 1
    for (int it = 0; it < nit; ++it) {
      const int kv0 = it * 128;
      const unsigned short* Kc = KsB + buf * 16384 + (whi * 64) * 128;
      const unsigned short* Vc = VsB + buf * 16384;
      if (it + 1 < nit) { loadK(kv0 + 128, buf ^ 1); loadV(kv0 + 128, buf ^ 1); }
      bf16x8 kreg[4][4];
      #pragma unroll
      for (int j = 0; j < 4; ++j)
        #pragma unroll
        for (int kk = 0; kk < 4; ++kk)
          kreg[j][kk] = *(const bf16x8*)&Kc[(j * 16 + lm) * 128 + kcol[kk]];
      floatx4 sa[2][4] = {};
      #pragma unroll
      for (int g = 0; g < 2; ++g)
        #pragma unroll
        for (int j = 0; j < 4; ++j)
          #pragma unroll
          for (int kk = 0; kk < 4; ++kk)
            sa[g][j] = __builtin_amdgcn_mfma_f32_16x16x32_bf16(qfr[g][kk], kreg[j][kk], sa[g][j], 0, 0, 0);
      bf16x8 ap[2][2];
      #pragma unroll
      for (int g = 0; g < 2; ++g) {
        const int rowb = Q0 + wlo * 32 + g * 16 + gq * 4;
        #pragma unroll
        for (int r = 0; r < 4; ++r) {
          const int qg = rowb + r;
          const int prow = gq * 4 + r;
          #pragma unroll
          for (int j = 0; j < 4; ++j) {
            const int kg = kv0 + whi * 64 + j * 16 + lm;
            const float p = (kg <= qg) ? __expf(sa[g][j][r]) : 0.0f;
            const int pcol = j * 16 + lm;
            psW[prow * 64 + (((pcol >> 3) ^ (prow & 7)) << 3) + (pcol & 7)] =
                __builtin_bit_cast(unsigned short, (__bf16)p);
          }
        }
        ap[g][0] = *(const bf16x8*)&psW[lm * 64 + ((gq ^ (lm & 7)) << 3)];
        ap[g][1] = *(const bf16x8*)&psW[lm * 64 + (((4 | gq) ^ (lm & 7)) << 3)];
      }
      #pragma unroll
      for (int jd = 0; jd < 8; ++jd) {
        const int row = (jd * 16 + lm) * 128;
        bf16x8 bv0 = *(const bf16x8*)&Vc[row + sw0];
        bf16x8 bv1 = *(const bf16x8*)&Vc[row + sw1];
        #pragma unroll
        for (int g = 0; g < 2; ++g) {
          acc_o[g][jd] = __builtin_amdgcn_mfma_f32_16x16x32_bf16(bv0, ap[g][0], acc_o[g][jd], 0, 0, 0);
          acc_o[g][jd] = __builtin_amdgcn_mfma_f32_16x16x32_bf16(bv1, ap[g][1], acc_o[g][jd], 0, 0, 0);
        }
      }
      #pragma unroll
      for (int g = 0; g < 2; ++g) {
        acc_l[g] = __builtin_amdgcn_mfma_f32_16x16x32_bf16(ones, ap[g][0], acc_l[g], 0, 0, 0);
        acc_l[g] = __builtin_amdgcn_mfma_f32_16x16x32_bf16(ones, ap[g][1], acc_l[g], 0, 0, 0);
      }
      asm volatile("s_waitcnt vmcnt(0) lgkmcnt(0)" ::: "memory");
      __builtin_amdgcn_s_barrier();
      buf ^= 1;
    }

    // combine parity partial sums via dead K/V LDS, whi==0 stores Z
    float* scO = (float*)KsB;
    float* scL = (float*)VsB;
    if (whi == 1) {
      #pragma unroll
      for (int g = 0; g < 2; ++g) {
        #pragma unroll
        for (int jd = 0; jd < 8; ++jd)
          #pragma unroll
          for (int r = 0; r < 4; ++r)
            scO[wlo * 4096 + (g * 32 + jd * 4 + r) * 64 + lane] = acc_o[g][jd][r];
        scL[wlo * 128 + g * 64 + lane] = acc_l[g][0];
      }
    }
    __syncthreads();
    if (whi == 0) {
      #pragma unroll
      for (int g = 0; g < 2; ++g) {
        const float inv = 1.0f / (acc_l[g][0] + scL[wlo * 128 + g * 64 + lane]);
        const size_t t_ = (size_t)b * S_LEN + Q0 + wlo * 32 + g * 16 + lm;
        #pragma unroll
        for (int jd = 0; jd < 8; ++jd) {
          ushortx4 pk;
          #pragma unroll
          for (int r = 0; r < 4; ++r)
            pk[r] = f2bf((acc_o[g][jd][r] + scO[wlo * 4096 + (g * 32 + jd * 4 + r) * 64 + lane]) * inv);
          *(ushortx4*)&Z[t_ * (NH * DH) + h * DH + jd * 16 + gq * 4] = pk;
        }
      }
    }
    __syncthreads();  // scratch/buffers dead before next pass's staging
  }
}

extern "C" void kernel_launch(void* const* d_in, const int* in_sizes, int n_in,
                              void* d_out, int out_size, void* d_ws, size_t ws_size,
                              hipStream_t stream) {
  (void)in_sizes; (void)n_in; (void)out_size; (void)ws_size;
  const float* q  = (const float*)d_in[0];
  const float* k  = (const float*)d_in[1];
  const float* v  = (const float*)d_in[2];
  const float* Wq = (const float*)d_in[3];
  const float* Wk = (const float*)d_in[4];
  const float* Wv = (const float*)d_in[5];
  const float* Wo = (const float*)d_in[6];

  unsigned short* Qh  = (unsigned short*)d_ws;
  unsigned short* Kh  = Qh + (size_t)2 * NH * S_LEN * DH;
  unsigned short* Vt  = Kh + (size_t)2 * KVH * S_LEN * DH;
  unsigned short* Z   = Vt + (size_t)2 * KVH * S_LEN * DH;
  unsigned short* vb  = Z + (size_t)4096 * 2048;
  unsigned short* Wqt = vb + (size_t)4096 * 2048;
  unsigned short* Wkt = Wqt + (size_t)2048 * 2048;
  unsigned short* Wvt = Wkt + (size_t)512 * 2048;
  unsigned short* Wot = Wvt + (size_t)512 * 2048;
  // qb/kb live in d_out (dead before out_kernel writes d_out)
  unsigned short* qb = (unsigned short*)d_out;
  unsigned short* kb = qb + (size_t)4096 * 2048;

  const float scale = 0.29730177875068026f;  // 128^(-1/4), folded into Wq/Wk

  static int s_attr_done = 0;
  if (!s_attr_done) {
    hipFuncSetAttribute(reinterpret_cast<const void*>(proj_kernel),
                        hipFuncAttributeMaxDynamicSharedMemorySize, 131072);
    hipFuncSetAttribute(reinterpret_cast<const void*>(out_kernel),
                        hipFuncAttributeMaxDynamicSharedMemorySize, 98304);
    hipFuncSetAttribute(reinterpret_cast<const void*>(attn_kernel),
                        hipFuncAttributeMaxDynamicSharedMemorySize, 147456);
    s_attr_done = 1;
  }

  pre_kernel<<<22528, 256, 0, stream>>>(q, k, v, Wq, Wk, Wv, Wo,
                                        qb, kb, vb, Wqt, Wkt, Wvt, Wot, scale);
  proj_kernel<<<192, 512, 131072, stream>>>(qb, kb, vb, Wqt, Wkt, Wvt, Qh, Kh, Vt);
  attn_kernel<<<dim3(8, 16, 2), 512, 147456, stream>>>(Qh, Kh, Vt, Z);
  out_kernel<<<256, 512, 98304, stream>>>(Z, Wot, (float*)d_out);
}

// Round 9
// 313.101 us; speedup vs baseline: 1.3304x; 1.0404x over previous
//
#include <hip/hip_runtime.h>

#define S_LEN 2048
#define EMB 2048
#define NH 16
#define KVH 4
#define DH 128

typedef __bf16 bf16x8 __attribute__((ext_vector_type(8)));
typedef float floatx4 __attribute__((ext_vector_type(4)));
typedef unsigned short ushortx8 __attribute__((ext_vector_type(8)));
typedef unsigned short ushortx4 __attribute__((ext_vector_type(4)));

static __device__ __forceinline__ unsigned short f2bf(float f) {
  unsigned u = __float_as_uint(f);
  return (unsigned short)((u + 0x7fffu + ((u >> 16) & 1u)) >> 16);
}
static __device__ __forceinline__ unsigned short cbf(float f) {
  return __builtin_bit_cast(unsigned short, (__bf16)f);
}

// async 16B global -> LDS (wave-uniform LDS base + lane*16)
static __device__ __forceinline__ void gload16(const unsigned short* g, unsigned short* l) {
  __builtin_amdgcn_global_load_lds(
      (const __attribute__((address_space(1))) unsigned int*)(const void*)g,
      (__attribute__((address_space(3))) unsigned int*)(void*)l, 16, 0, 0);
}

// ---- fused preprocessing:
// blocks 0..2559: weight transpose/scale 64x64 tiles (float4 loads, full-row
//   ushortx8 stores, stride-65 LDS). Dispatched FIRST so the kernel tail is
//   the high-BW streaming part.
// blocks 2560..8703: qkv fp32->bf16, 16 elems/thread, packed casts.
__global__ __launch_bounds__(256) void pre_kernel(
    const float* __restrict__ q, const float* __restrict__ k, const float* __restrict__ v,
    const float* __restrict__ Wq, const float* __restrict__ Wk,
    const float* __restrict__ Wv, const float* __restrict__ Wo,
    unsigned short* __restrict__ qo, unsigned short* __restrict__ ko,
    unsigned short* __restrict__ vo,
    unsigned short* __restrict__ Wqt, unsigned short* __restrict__ Wkt,
    unsigned short* __restrict__ Wvt, unsigned short* __restrict__ Wot,
    float scale) {
  int bx = blockIdx.x;
  if (bx < 2560) {
    __shared__ float Ls[64 * 65];
    const float* W; unsigned short* Wt; int N, tile; float sc;
    if (bx < 1024)      { W = Wq; Wt = Wqt; N = 2048; tile = bx;        sc = scale; }
    else if (bx < 1280) { W = Wk; Wt = Wkt; N = 512;  tile = bx - 1024; sc = scale; }
    else if (bx < 1536) { W = Wv; Wt = Wvt; N = 512;  tile = bx - 1280; sc = 1.0f; }
    else                { W = Wo; Wt = Wot; N = 2048; tile = bx - 1536; sc = 1.0f; }
    const int ntiles = N >> 6;
    const int n0 = (tile % ntiles) * 64, k0 = (tile / ntiles) * 64;
    const int t = threadIdx.x;
    const int c4 = t & 15, kr = t >> 4;
    #pragma unroll
    for (int p = 0; p < 4; ++p) {
      const int row = kr + p * 16;
      const floatx4 vv = *(const floatx4*)&W[(size_t)(k0 + row) * N + n0 + c4 * 4];
      #pragma unroll
      for (int c = 0; c < 4; ++c) Ls[row * 65 + c4 * 4 + c] = vv[c];
    }
    __syncthreads();
    const int kc = t & 7, nr = t >> 3;  // 8 k-chunks x 32 n-rows per pass
    #pragma unroll
    for (int p = 0; p < 2; ++p) {
      const int n = nr + p * 32;
      ushortx8 o;
      #pragma unroll
      for (int j = 0; j < 8; ++j) o[j] = cbf(Ls[(kc * 8 + j) * 65 + n] * sc);
      *(ushortx8*)&Wt[(size_t)(n0 + n) * 2048 + k0 + kc * 8] = o;
    }
  } else {
    const int bb = bx - 2560;            // 0..6143, 2048 blocks per tensor
    const int sel = bb >> 11;
    const float* in = (sel == 0) ? q : (sel == 1) ? k : v;
    unsigned short* out = (sel == 0) ? qo : (sel == 1) ? ko : vo;
    size_t i = (((size_t)(bb & 2047)) * 256 + threadIdx.x) * 16;
    floatx4 a0 = *(const floatx4*)(in + i);
    floatx4 a1 = *(const floatx4*)(in + i + 4);
    floatx4 a2 = *(const floatx4*)(in + i + 8);
    floatx4 a3 = *(const floatx4*)(in + i + 12);
    ushortx8 o0, o1;
    #pragma unroll
    for (int c = 0; c < 4; ++c) {
      o0[c] = cbf(a0[c]); o0[4 + c] = cbf(a1[c]);
      o1[c] = cbf(a2[c]); o1[4 + c] = cbf(a3[c]);
    }
    *(ushortx8*)(out + i) = o0;
    *(ushortx8*)(out + i + 8) = o1;
  }
}

// ================= 256x256 / BK=64 / 8-wave / 8-phase GEMM core =================
static __device__ __forceinline__ void gemm256_core(
    const unsigned short* __restrict__ Ab, const unsigned short* __restrict__ Bb,
    bool swap, unsigned short* As, unsigned short* Bs, floatx4 (&acc)[8][4]) {
  const int tid = threadIdx.x;
  const int lane = tid & 63, w = tid >> 6;
  const int lm = lane & 15, gq = lane >> 4;
  const int wm = w >> 2, wn = w & 3;
  const int lr = lane >> 3, lc = (lane & 7) ^ lr;

  auto stageH = [&](const unsigned short* gb, unsigned short* lt, int half, int kst) {
    #pragma unroll
    for (int qq = 0; qq < 2; ++qq) {
      const int rb = half * 128 + w * 16 + qq * 8;
      gload16(gb + (((size_t)(rb + lr)) << 11) + kst + (lc << 3), lt + rb * 64);
    }
  };

  unsigned short* As2 = As + 16384;
  unsigned short* Bs2 = Bs + 16384;

  stageH(Ab, As, 0, 0);  stageH(Ab, As, 1, 0);
  stageH(Bb, Bs, 0, 0);  stageH(Bb, Bs, 1, 0);
  stageH(Ab, As2, 0, 64);
  asm volatile("s_waitcnt vmcnt(2)" ::: "memory");
  __builtin_amdgcn_s_barrier();

  const int r1 = (wm * 128 + lm) * 64;
  const int r2 = (wn * 64 + lm) * 64;
  const int c0 = ((0 + gq) ^ (lm & 7)) * 8;
  const int c1 = ((4 + gq) ^ (lm & 7)) * 8;

#define TILE_BODY(CA, CB, OA, OB, KS1, KS2, STG1, STG4)                                         \
  {                                                                                             \
    const unsigned short* l1 = swap ? (CB) : (CA);                                              \
    const unsigned short* l2 = swap ? (CA) : (CB);                                              \
    bf16x8 op1[8], o2a[4], o2b[4];                                                              \
    _Pragma("unroll") for (int i = 0; i < 8; ++i)                                               \
      op1[i] = *(const bf16x8*)&l1[r1 + i * 1024 + c0];                                         \
    _Pragma("unroll") for (int j = 0; j < 4; ++j)                                               \
      o2a[j] = *(const bf16x8*)&l2[r2 + j * 1024 + c0];                                         \
    if (STG1) stageH(Ab, (OA), 1, (KS1));                                                       \
    __builtin_amdgcn_s_barrier();                                                               \
    asm volatile("s_waitcnt lgkmcnt(0)" ::: "memory");                                          \
    __builtin_amdgcn_s_setprio(1);                                                              \
    _Pragma("unroll") for (int i = 0; i < 8; ++i) {                                             \
      acc[i][0] = __builtin_amdgcn_mfma_f32_16x16x32_bf16(op1[i], o2a[0], acc[i][0], 0, 0, 0);  \
      acc[i][1] = __builtin_amdgcn_mfma_f32_16x16x32_bf16(op1[i], o2a[1], acc[i][1], 0, 0, 0);  \
    }                                                                                           \
    __builtin_amdgcn_s_setprio(0);                                                              \
    __builtin_amdgcn_s_barrier();                                                               \
    _Pragma("unroll") for (int j = 0; j < 4; ++j)                                               \
      o2b[j] = *(const bf16x8*)&l2[r2 + j * 1024 + c1];                                         \
    if (STG1) stageH(Bb, (OB), 0, (KS1));                                                       \
    __builtin_amdgcn_s_barrier();                                                               \
    asm volatile("s_waitcnt lgkmcnt(0)" ::: "memory");                                          \
    __builtin_amdgcn_s_setprio(1);                                                              \
    _Pragma("unroll") for (int i = 0; i < 8; ++i) {                                             \
      acc[i][2] = __builtin_amdgcn_mfma_f32_16x16x32_bf16(op1[i], o2a[2], acc[i][2], 0, 0, 0);  \
      acc[i][3] = __builtin_amdgcn_mfma_f32_16x16x32_bf16(op1[i], o2a[3], acc[i][3], 0, 0, 0);  \
    }                                                                                           \
    __builtin_amdgcn_s_setprio(0);                                                               \
    __builtin_amdgcn_s_barrier();                                                               \
    _Pragma("unroll") for (int i = 0; i < 8; ++i)                                               \
      op1[i] = *(const bf16x8*)&l1[r1 + i * 1024 + c1];                                         \
    if (STG1) stageH(Bb, (OB), 1, (KS1));                                                       \
    __builtin_amdgcn_s_barrier();                                                               \
    asm volatile("s_waitcnt lgkmcnt(0)" ::: "memory");                                          \
    __builtin_amdgcn_s_setprio(1);                                                              \
    _Pragma("unroll") for (int i = 0; i < 8; ++i) {                                             \
      acc[i][0] = __builtin_amdgcn_mfma_f32_16x16x32_bf16(op1[i], o2b[0], acc[i][0], 0, 0, 0);  \
      acc[i][1] = __builtin_amdgcn_mfma_f32_16x16x32_bf16(op1[i], o2b[1], acc[i][1], 0, 0, 0);  \
    }                                                                                           \
    __builtin_amdgcn_s_setprio(0);                                                               \
    __builtin_amdgcn_s_barrier();                                                               \
    if (STG4) stageH(Ab, (CA), 0, (KS2));                                                       \
    __builtin_amdgcn_s_barrier();                                                               \
    __builtin_amdgcn_s_setprio(1);                                                              \
    _Pragma("unroll") for (int i = 0; i < 8; ++i) {                                             \
      acc[i][2] = __builtin_amdgcn_mfma_f32_16x16x32_bf16(op1[i], o2b[2], acc[i][2], 0, 0, 0);  \
      acc[i][3] = __builtin_amdgcn_mfma_f32_16x16x32_bf16(op1[i], o2b[3], acc[i][3], 0, 0, 0);  \
    }                                                                                           \
    __builtin_amdgcn_s_setprio(0);                                                               \
    if (STG4) { asm volatile("s_waitcnt vmcnt(2)" ::: "memory"); }                              \
    else      { asm volatile("s_waitcnt vmcnt(0)" ::: "memory"); }                              \
    __builtin_amdgcn_s_barrier();                                                               \
  }

  #pragma unroll 1
  for (int t = 0; t < 30; t += 2) {
    TILE_BODY(As, Bs, As2, Bs2, (t + 1) * 64, (t + 2) * 64, 1, 1);
    TILE_BODY(As2, Bs2, As, Bs, (t + 2) * 64, (t + 3) * 64, 1, 1);
  }
  TILE_BODY(As, Bs, As2, Bs2, 31 * 64, 0, 1, 0);
  TILE_BODY(As2, Bs2, As, Bs, 0, 0, 0, 0);
#undef TILE_BODY
}

// ========== 256(big,op2) x 128(small,op1) / BK=64 core (for out_kernel) ==========
static __device__ __forceinline__ void gemm_bs_core(
    const unsigned short* __restrict__ Bigb, const unsigned short* __restrict__ Smb,
    unsigned short* As, unsigned short* Bs, floatx4 (&acc)[4][4]) {
  const int tid = threadIdx.x;
  const int lane = tid & 63, w = tid >> 6;
  const int lm = lane & 15, gq = lane >> 4;
  const int wm = w >> 2, wn = w & 3;
  const int lr = lane >> 3, lc = (lane & 7) ^ lr;

  auto stageH = [&](const unsigned short* gb, unsigned short* lt, int half, int kst) {
    #pragma unroll
    for (int qq = 0; qq < 2; ++qq) {
      const int rb = half * 128 + w * 16 + qq * 8;
      gload16(gb + (((size_t)(rb + lr)) << 11) + kst + (lc << 3), lt + rb * 64);
    }
  };

  unsigned short* As2 = As + 16384;
  unsigned short* Bs2 = Bs + 8192;

  stageH(Bigb, As, 0, 0);  stageH(Bigb, As, 1, 0);
  stageH(Smb, Bs, 0, 0);
  stageH(Bigb, As2, 0, 64);
  asm volatile("s_waitcnt vmcnt(2)" ::: "memory");
  __builtin_amdgcn_s_barrier();

  const int r1 = (wm * 64 + lm) * 64;
  const int r2 = (wn * 64 + lm) * 64;
  const int c0 = ((0 + gq) ^ (lm & 7)) * 8;
  const int c1 = ((4 + gq) ^ (lm & 7)) * 8;

#define TB(CA, CB, OA, OB, KS1, KS2, STG1, STG4)                                                \
  {                                                                                             \
    bf16x8 op1[4], o2a[4], o2b[4];                                                              \
    _Pragma("unroll") for (int i = 0; i < 4; ++i)                                               \
      op1[i] = *(const bf16x8*)&(CB)[r1 + i * 1024 + c0];                                       \
    _Pragma("unroll") for (int j = 0; j < 4; ++j)                                               \
      o2a[j] = *(const bf16x8*)&(CA)[r2 + j * 1024 + c0];                                       \
    if (STG1) stageH(Bigb, (OA), 1, (KS1));                                                     \
    __builtin_amdgcn_s_barrier();                                                               \
    asm volatile("s_waitcnt lgkmcnt(0)" ::: "memory");                                          \
    __builtin_amdgcn_s_setprio(1);                                                              \
    _Pragma("unroll") for (int i = 0; i < 4; ++i) {                                             \
      acc[i][0] = __builtin_amdgcn_mfma_f32_16x16x32_bf16(op1[i], o2a[0], acc[i][0], 0, 0, 0);  \
      acc[i][1] = __builtin_amdgcn_mfma_f32_16x16x32_bf16(op1[i], o2a[1], acc[i][1], 0, 0, 0);  \
    }                                                                                           \
    __builtin_amdgcn_s_setprio(0);                                                              \
    __builtin_amdgcn_s_barrier();                                                               \
    _Pragma("unroll") for (int j = 0; j < 4; ++j)                                               \
      o2b[j] = *(const bf16x8*)&(CA)[r2 + j * 1024 + c1];                                       \
    if (STG1) stageH(Smb, (OB), 0, (KS1));                                                      \
    __builtin_amdgcn_s_barrier();                                                               \
    asm volatile("s_waitcnt lgkmcnt(0)" ::: "memory");                                          \
    __builtin_amdgcn_s_setprio(1);                                                              \
    _Pragma("unroll") for (int i = 0; i < 4; ++i) {                                             \
      acc[i][2] = __builtin_amdgcn_mfma_f32_16x16x32_bf16(op1[i], o2a[2], acc[i][2], 0, 0, 0);  \
      acc[i][3] = __builtin_amdgcn_mfma_f32_16x16x32_bf16(op1[i], o2a[3], acc[i][3], 0, 0, 0);  \
    }                                                                                           \
    __builtin_amdgcn_s_setprio(0);                                                              \
    __builtin_amdgcn_s_barrier();                                                               \
    _Pragma("unroll") for (int i = 0; i < 4; ++i)                                               \
      op1[i] = *(const bf16x8*)&(CB)[r1 + i * 1024 + c1];                                       \
    __builtin_amdgcn_s_barrier();                                                               \
    asm volatile("s_waitcnt lgkmcnt(0)" ::: "memory");                                          \
    __builtin_amdgcn_s_setprio(1);                                                              \
    _Pragma("unroll") for (int i = 0; i < 4; ++i) {                                             \
      acc[i][0] = __builtin_amdgcn_mfma_f32_16x16x32_bf16(op1[i], o2b[0], acc[i][0], 0, 0, 0);  \
      acc[i][1] = __builtin_amdgcn_mfma_f32_16x16x32_bf16(op1[i], o2b[1], acc[i][1], 0, 0, 0);  \
    }                                                                                           \
    __builtin_amdgcn_s_setprio(0);                                                              \
    __builtin_amdgcn_s_barrier();                                                               \
    if (STG4) stageH(Bigb, (CA), 0, (KS2));                                                     \
    __builtin_amdgcn_s_barrier();                                                               \
    __builtin_amdgcn_s_setprio(1);                                                              \
    _Pragma("unroll") for (int i = 0; i < 4; ++i) {                                             \
      acc[i][2] = __builtin_amdgcn_mfma_f32_16x16x32_bf16(op1[i], o2b[2], acc[i][2], 0, 0, 0);  \
      acc[i][3] = __builtin_amdgcn_mfma_f32_16x16x32_bf16(op1[i], o2b[3], acc[i][3], 0, 0, 0);  \
    }                                                                                           \
    __builtin_amdgcn_s_setprio(0);                                                              \
    if (STG4) { asm volatile("s_waitcnt vmcnt(2)" ::: "memory"); }                              \
    else      { asm volatile("s_waitcnt vmcnt(0)" ::: "memory"); }                              \
    __builtin_amdgcn_s_barrier();                                                               \
  }

  #pragma unroll 1
  for (int t = 0; t < 30; t += 2) {
    TB(As, Bs, As2, Bs2, (t + 1) * 64, (t + 2) * 64, 1, 1);
    TB(As2, Bs2, As, Bs, (t + 2) * 64, (t + 3) * 64, 1, 1);
  }
  TB(As, Bs, As2, Bs2, 31 * 64, 0, 1, 0);
  TB(As2, Bs2, As, Bs, 0, 0, 0, 0);
#undef TB
}

// ---- merged Q/K/V projection GEMM: 192 blocks of 256x256, K=2048 ----
__global__ __launch_bounds__(512, 2) void proj_kernel(
    const unsigned short* __restrict__ qb, const unsigned short* __restrict__ kb,
    const unsigned short* __restrict__ vb,
    const unsigned short* __restrict__ Wqt, const unsigned short* __restrict__ Wkt,
    const unsigned short* __restrict__ Wvt,
    unsigned short* __restrict__ Qh, unsigned short* __restrict__ Kh,
    unsigned short* __restrict__ Vt) {
  extern __shared__ unsigned short lds[];
  unsigned short* As = lds;
  unsigned short* Bs = lds + 32768;
  int bid = (int)blockIdx.x;
  bid = (bid & 7) * 24 + (bid >> 3);
  const unsigned short *Ab, *Bb;
  int task, bn, bt;
  if (bid < 128)      { task = 0; bn = bid >> 4;         bt = bid & 15;         Ab = qb; Bb = Wqt; }
  else if (bid < 160) { task = 1; bn = (bid - 128) >> 4; bt = (bid - 128) & 15; Ab = kb; Bb = Wkt; }
  else                { task = 2; bn = (bid - 160) >> 4; bt = (bid - 160) & 15; Ab = vb; Bb = Wvt; }
  Ab += ((size_t)bt) << 19;
  Bb += ((size_t)bn) << 19;

  floatx4 acc[8][4] = {};
  gemm256_core(Ab, Bb, task != 2, As, Bs, acc);

  const int tid = threadIdx.x, lane = tid & 63, w = tid >> 6;
  const int lm = lane & 15, gq = lane >> 4;
  const int wm = w >> 2, wn = w & 3;
  if (task != 2) {
    unsigned short* outp = (task == 0) ? Qh : Kh;
    const int nheads = (task == 0) ? NH : KVH;
    const int head = bn * 2 + wm;
    #pragma unroll
    for (int i = 0; i < 8; ++i) {
      const int d0 = i * 16 + gq * 4;
      #pragma unroll
      for (int j = 0; j < 4; ++j) {
        const int tg = bt * 256 + wn * 64 + j * 16 + lm;
        const int b_ = tg >> 11, s_ = tg & 2047;
        ushortx4 pk;
        #pragma unroll
        for (int r = 0; r < 4; ++r) pk[r] = f2bf(acc[i][j][r]);
        *(ushortx4*)&outp[((size_t)(b_ * nheads + head) * S_LEN + s_) * DH + d0] = pk;
      }
    }
  } else {
    #pragma unroll
    for (int i = 0; i < 8; ++i) {
      const int sgl = bt * 256 + wm * 128 + i * 16 + gq * 4;
      const int b_ = sgl >> 11, s_ = sgl & 2047;
      #pragma unroll
      for (int j = 0; j < 4; ++j) {
        const int dl = wn * 64 + j * 16;
        const int head = bn * 2 + (dl >> 7);
        const int dd = (dl & 127) + lm;
        ushortx4 pk;
        #pragma unroll
        for (int r = 0; r < 4; ++r) pk[r] = f2bf(acc[i][j][r]);
        *(ushortx4*)&Vt[((size_t)(b_ * KVH + head) * DH + dd) * S_LEN + s_] = pk;
      }
    }
  }
}

// ---- final GEMM: 256 blocks of 256t x 128n (100% CU fill) ----
__global__ __launch_bounds__(512, 1) void out_kernel(const unsigned short* __restrict__ Z,
                                                     const unsigned short* __restrict__ Wot,
                                                     float* __restrict__ outp) {
  extern __shared__ unsigned short lds[];
  unsigned short* As = lds;
  unsigned short* Bs = lds + 32768;
  int bid = (int)blockIdx.x;
  bid = (bid & 7) * 32 + (bid >> 3);
  const int bn = bid >> 4, bt = bid & 15;

  floatx4 acc[4][4] = {};
  gemm_bs_core(Z + (((size_t)bt) << 19), Wot + (((size_t)bn) << 18), As, Bs, acc);

  const int tid = threadIdx.x, lane = tid & 63, w = tid >> 6;
  const int lm = lane & 15, gq = lane >> 4;
  const int wm = w >> 2, wn = w & 3;
  #pragma unroll
  for (int i = 0; i < 4; ++i) {
    const int n0 = bn * 128 + wm * 64 + i * 16 + gq * 4;
    #pragma unroll
    for (int j = 0; j < 4; ++j) {
      const int tg = bt * 256 + wn * 64 + j * 16 + lm;
      *(floatx4*)&outp[(size_t)tg * 2048 + n0] = acc[i][j];
    }
  }
}

// ---- flash-style causal attention, 8-wave kv-split wave pairs.
// Ps row stride 68 u16 (34 dwords == 2 mod 32): the 4 gq-groups' rows land on
// distinct bank offsets -> u16 write conflicts collapse. Reads use 2x b64.
__global__ __launch_bounds__(512, 2) void attn_kernel(const unsigned short* __restrict__ Qh,
                                                      const unsigned short* __restrict__ Kh,
                                                      const unsigned short* __restrict__ Vt,
                                                      unsigned short* __restrict__ Z) {
  extern __shared__ unsigned short alds[];
  unsigned short* KsB = alds;            // 2 x [128][128] = 65536 B
  unsigned short* VsB = alds + 32768;    // 2 x [128 d][128 s] = 65536 B
  unsigned short* PsB = alds + 65536;    // 8 waves x [16][68] = 17408 B (total 148480)
  const int tid = threadIdx.x;
  const int w = tid >> 6, lane = tid & 63;
  const int wlo = w & 3, whi = w >> 2;
  const int lm = lane & 15, gq = lane >> 4;
  const int h = blockIdx.y, b = blockIdx.z;
  const unsigned short* Kp = Kh + (size_t)(b * KVH + (h >> 2)) * S_LEN * DH;
  const unsigned short* Vp = Vt + (size_t)(b * KVH + (h >> 2)) * DH * S_LEN;
  unsigned short* psW = PsB + w * (16 * 68);

  const int dr = lane >> 4;
  const int srcswz = ((lane & 15) ^ ((w * 4 + dr) & 7)) * 8;
  auto loadK = [&](int kv, int bsel) {
    unsigned short* dst = KsB + bsel * 16384 + w * 512;
    #pragma unroll
    for (int i = 0; i < 4; ++i)
      gload16(Kp + (size_t)(kv + i * 32 + w * 4 + dr) * DH + srcswz, dst + i * 4096);
  };
  auto loadV = [&](int kv, int bsel) {
    unsigned short* dst = VsB + bsel * 16384 + w * 512;
    #pragma unroll
    for (int i = 0; i < 4; ++i)
      gload16(Vp + (size_t)(i * 32 + w * 4 + dr) * S_LEN + kv + srcswz, dst + i * 4096);
  };

  int kcol[4];
  #pragma unroll
  for (int kk = 0; kk < 4; ++kk) kcol[kk] = ((kk * 4 + gq) ^ (lm & 7)) * 8;
  const int sw0 = (whi * 8 + (gq ^ (lm & 7))) * 8;
  const int sw1 = (whi * 8 + ((4 | gq) ^ (lm & 7))) * 8;

  bf16x8 ones;
  #pragma unroll
  for (int c = 0; c < 8; ++c) ones[c] = (__bf16)1.0f;

  #pragma unroll 1
  for (int pass = 0; pass < 2; ++pass) {
    const int qt = pass ? (int)blockIdx.x : 15 - (int)blockIdx.x;
    const int Q0 = qt * 128;
    const int nit = qt + 1;
    const unsigned short* Qp = Qh + ((size_t)(b * NH + h) * S_LEN + Q0) * DH;
    bf16x8 qfr[2][4];
    #pragma unroll
    for (int g = 0; g < 2; ++g)
      #pragma unroll
      for (int kk = 0; kk < 4; ++kk)
        qfr[g][kk] = *(const bf16x8*)(Qp + (size_t)(wlo * 32 + g * 16 + lm) * DH + kk * 32 + gq * 8);

    floatx4 acc_o[2][8] = {};
    floatx4 acc_l[2] = {};

    loadK(0, 0);
    loadV(0, 0);
    asm volatile("s_waitcnt vmcnt(0)" ::: "memory");
    __builtin_amdgcn_s_barrier();
    int buf = 0;

    #pragma unroll 1
    for (int it = 0; it < nit; ++it) {
      const int kv0 = it * 128;
      const unsigned short* Kc = KsB + buf * 16384 + (whi * 64) * 128;
      const unsigned short* Vc = VsB + buf * 16384;
      if (it + 1 < nit) { loadK(kv0 + 128, buf ^ 1); loadV(kv0 + 128, buf ^ 1); }
      bf16x8 kreg[4][4];
      #pragma unroll
      for (int j = 0; j < 4; ++j)
        #pragma unroll
        for (int kk = 0; kk < 4; ++kk)
          kreg[j][kk] = *(const bf16x8*)&Kc[(j * 16 + lm) * 128 + kcol[kk]];
      floatx4 sa[2][4] = {};
      #pragma unroll
      for (int g = 0; g < 2; ++g)
        #pragma unroll
        for (int j = 0; j < 4; ++j)
          #pragma unroll
          for (int kk = 0; kk < 4; ++kk)
            sa[g][j] = __builtin_amdgcn_mfma_f32_16x16x32_bf16(qfr[g][kk], kreg[j][kk], sa[g][j], 0, 0, 0);
      bf16x8 ap[2][2];
      #pragma unroll
      for (int g = 0; g < 2; ++g) {
        const int rowb = Q0 + wlo * 32 + g * 16 + gq * 4;
        #pragma unroll
        for (int r = 0; r < 4; ++r) {
          const int qg = rowb + r;
          const int prow = gq * 4 + r;
          #pragma unroll
          for (int j = 0; j < 4; ++j) {
            const int kg = kv0 + whi * 64 + j * 16 + lm;
            const float p = (kg <= qg) ? __expf(sa[g][j][r]) : 0.0f;
            const int pcol = j * 16 + lm;
            psW[prow * 68 + (((pcol >> 3) ^ (prow & 7)) << 3) + (pcol & 7)] = cbf(p);
          }
        }
        {
          const int cs0 = (gq ^ (lm & 7)) << 3;
          const int cs1 = ((4 | gq) ^ (lm & 7)) << 3;
          union PsRd { ushortx4 h[2]; bf16x8 bv; } c0, c1;
          c0.h[0] = *(const ushortx4*)&psW[lm * 68 + cs0];
          c0.h[1] = *(const ushortx4*)&psW[lm * 68 + cs0 + 4];
          c1.h[0] = *(const ushortx4*)&psW[lm * 68 + cs1];
          c1.h[1] = *(const ushortx4*)&psW[lm * 68 + cs1 + 4];
          ap[g][0] = c0.bv;
          ap[g][1] = c1.bv;
        }
      }
      #pragma unroll
      for (int jd = 0; jd < 8; ++jd) {
        const int row = (jd * 16 + lm) * 128;
        bf16x8 bv0 = *(const bf16x8*)&Vc[row + sw0];
        bf16x8 bv1 = *(const bf16x8*)&Vc[row + sw1];
        #pragma unroll
        for (int g = 0; g < 2; ++g) {
          acc_o[g][jd] = __builtin_amdgcn_mfma_f32_16x16x32_bf16(bv0, ap[g][0], acc_o[g][jd], 0, 0, 0);
          acc_o[g][jd] = __builtin_amdgcn_mfma_f32_16x16x32_bf16(bv1, ap[g][1], acc_o[g][jd], 0, 0, 0);
        }
      }
      #pragma unroll
      for (int g = 0; g < 2; ++g) {
        acc_l[g] = __builtin_amdgcn_mfma_f32_16x16x32_bf16(ones, ap[g][0], acc_l[g], 0, 0, 0);
        acc_l[g] = __builtin_amdgcn_mfma_f32_16x16x32_bf16(ones, ap[g][1], acc_l[g], 0, 0, 0);
      }
      asm volatile("s_waitcnt vmcnt(0) lgkmcnt(0)" ::: "memory");
      __builtin_amdgcn_s_barrier();
      buf ^= 1;
    }

    // combine parity partial sums via dead K/V LDS, whi==0 stores Z
    float* scO = (float*)KsB;
    float* scL = (float*)VsB;
    if (whi == 1) {
      #pragma unroll
      for (int g = 0; g < 2; ++g) {
        #pragma unroll
        for (int jd = 0; jd < 8; ++jd)
          #pragma unroll
          for (int r = 0; r < 4; ++r)
            scO[wlo * 4096 + (g * 32 + jd * 4 + r) * 64 + lane] = acc_o[g][jd][r];
        scL[wlo * 128 + g * 64 + lane] = acc_l[g][0];
      }
    }
    __syncthreads();
    if (whi == 0) {
      #pragma unroll
      for (int g = 0; g < 2; ++g) {
        const float inv = 1.0f / (acc_l[g][0] + scL[wlo * 128 + g * 64 + lane]);
        const size_t t_ = (size_t)b * S_LEN + Q0 + wlo * 32 + g * 16 + lm;
        #pragma unroll
        for (int jd = 0; jd < 8; ++jd) {
          ushortx4 pk;
          #pragma unroll
          for (int r = 0; r < 4; ++r)
            pk[r] = f2bf((acc_o[g][jd][r] + scO[wlo * 4096 + (g * 32 + jd * 4 + r) * 64 + lane]) * inv);
          *(ushortx4*)&Z[t_ * (NH * DH) + h * DH + jd * 16 + gq * 4] = pk;
        }
      }
    }
    __syncthreads();
  }
}

extern "C" void kernel_launch(void* const* d_in, const int* in_sizes, int n_in,
                              void* d_out, int out_size, void* d_ws, size_t ws_size,
                              hipStream_t stream) {
  (void)in_sizes; (void)n_in; (void)out_size; (void)ws_size;
  const float* q  = (const float*)d_in[0];
  const float* k  = (const float*)d_in[1];
  const float* v  = (const float*)d_in[2];
  const float* Wq = (const float*)d_in[3];
  const float* Wk = (const float*)d_in[4];
  const float* Wv = (const float*)d_in[5];
  const float* Wo = (const float*)d_in[6];

  unsigned short* Qh  = (unsigned short*)d_ws;
  unsigned short* Kh  = Qh + (size_t)2 * NH * S_LEN * DH;
  unsigned short* Vt  = Kh + (size_t)2 * KVH * S_LEN * DH;
  unsigned short* Z   = Vt + (size_t)2 * KVH * S_LEN * DH;
  unsigned short* vb  = Z + (size_t)4096 * 2048;
  unsigned short* Wqt = vb + (size_t)4096 * 2048;
  unsigned short* Wkt = Wqt + (size_t)2048 * 2048;
  unsigned short* Wvt = Wkt + (size_t)512 * 2048;
  unsigned short* Wot = Wvt + (size_t)512 * 2048;
  // qb/kb live in d_out (dead before out_kernel writes d_out)
  unsigned short* qb = (unsigned short*)d_out;
  unsigned short* kb = qb + (size_t)4096 * 2048;

  const float scale = 0.29730177875068026f;  // 128^(-1/4), folded into Wq/Wk

  static int s_attr_done = 0;
  if (!s_attr_done) {
    (void)hipFuncSetAttribute(reinterpret_cast<const void*>(proj_kernel),
                              hipFuncAttributeMaxDynamicSharedMemorySize, 131072);
    (void)hipFuncSetAttribute(reinterpret_cast<const void*>(out_kernel),
                              hipFuncAttributeMaxDynamicSharedMemorySize, 98304);
    (void)hipFuncSetAttribute(reinterpret_cast<const void*>(attn_kernel),
                              hipFuncAttributeMaxDynamicSharedMemorySize, 148480);
    s_attr_done = 1;
  }

  pre_kernel<<<8704, 256, 0, stream>>>(q, k, v, Wq, Wk, Wv, Wo,
                                       qb, kb, vb, Wqt, Wkt, Wvt, Wot, scale);
  proj_kernel<<<192, 512, 131072, stream>>>(qb, kb, vb, Wqt, Wkt, Wvt, Qh, Kh, Vt);
  attn_kernel<<<dim3(8, 16, 2), 512, 148480, stream>>>(Qh, Kh, Vt, Z);
  out_kernel<<<256, 512, 98304, stream>>>(Z, Wot, (float*)d_out);
}